// Round 12
// baseline (845.408 us; speedup 1.0000x reference)
//
#include <hip/hip_runtime.h>
#include <math.h>

// AttnBlock: GroupNorm -> QKV 1x1 conv -> spatial self-attention -> proj 1x1 conv + residual
// x (4, 512, 64, 64) fp32. B=4, C=512, N=HW=4096, 32 groups of 16 ch.
// Round 12: attn v6 — lean-state occupancy design. QK K-dim split across 4
// ci-waves (qf 16 VGPR), partial-score LDS exchange, wave-local softmax,
// PV c-quarter per wave (acc 32 VGPR), V direct from L2, K LDS single-buffer.
// ~90 VGPR / 53 KB LDS -> 2-3 blocks/CU (vs r10's hard 1-block 2-wave/SIMD wall).

#define BATCH 4
#define CH    512
#define NPOS  4096
#define NGRP  32
#define GSIZE (16 * NPOS)
#define WSZ   262144   // 512*512

typedef __attribute__((ext_vector_type(8))) short bf16x8;
typedef __attribute__((ext_vector_type(4))) float f32x4;

__device__ __forceinline__ ushort f2b(float x) {   // fp32 -> bf16 RNE
    uint u = __float_as_uint(x);
    u += 0x7fff + ((u >> 16) & 1);
    return (ushort)(u >> 16);
}

// async global->LDS, 16B per lane (lds base wave-uniform, HW adds lane*16)
__device__ __forceinline__ void gld16(void* lds, const void* g) {
    __builtin_amdgcn_global_load_lds(
        (const __attribute__((address_space(1))) void*)g,
        (__attribute__((address_space(3))) void*)lds, 16, 0, 0);
}

// ---------------------------------------------------------------------------
// K1: GroupNorm statistics. One block per (b, g) contiguous 65536-float segment.
// ---------------------------------------------------------------------------
__global__ __launch_bounds__(256) void gn_stats_k(const float* __restrict__ x,
                                                  float* __restrict__ stats) {
    int bg = blockIdx.x;
    const float4* xp = reinterpret_cast<const float4*>(x + (size_t)bg * GSIZE);
    float s1 = 0.f, s2 = 0.f;
    for (int i = threadIdx.x; i < GSIZE / 4; i += 256) {
        float4 v = xp[i];
        s1 += v.x + v.y + v.z + v.w;
        s2 += v.x * v.x + v.y * v.y + v.z * v.z + v.w * v.w;
    }
    for (int off = 32; off > 0; off >>= 1) {
        s1 += __shfl_down(s1, off);
        s2 += __shfl_down(s2, off);
    }
    __shared__ float r1[4], r2[4];
    int wid = threadIdx.x >> 6;
    if ((threadIdx.x & 63) == 0) { r1[wid] = s1; r2[wid] = s2; }
    __syncthreads();
    if (threadIdx.x == 0) {
        float t1 = r1[0] + r1[1] + r1[2] + r1[3];
        float t2 = r2[0] + r2[1] + r2[2] + r2[3];
        float mean = t1 / (float)GSIZE;
        float var  = t2 / (float)GSIZE - mean * mean;
        stats[bg]       = mean;
        stats[128 + bg] = rsqrtf(var + 1e-6f);
    }
}

// ---------------------------------------------------------------------------
// K2a: weights fp32 -> bf16, W4[sel][o][c], sel = q,k,v,p.
// ---------------------------------------------------------------------------
__global__ __launch_bounds__(256) void wcvt_k(
    const float* __restrict__ Wq, const float* __restrict__ Wk,
    const float* __restrict__ Wv, const float* __restrict__ Wp,
    ushort* __restrict__ W4) {
    int id = blockIdx.x;             // 512 blocks
    int sel = id >> 7, blk = id & 127;
    const float* src = sel == 0 ? Wq : (sel == 1 ? Wk : (sel == 2 ? Wv : Wp));
    const float4* s4 = (const float4*)(src + (size_t)blk * 2048);
    ushort4* d4 = (ushort4*)(W4 + (size_t)sel * WSZ + (size_t)blk * 2048);
    for (int i = threadIdx.x; i < 512; i += 256) {
        float4 v = s4[i];
        d4[i] = make_ushort4(f2b(v.x), f2b(v.y), f2b(v.z), f2b(v.w));
    }
}

// ---------------------------------------------------------------------------
// K2b: GroupNorm apply + transpose: x[b][c][m] fp32 -> hnT[b][m][c] bf16.
// grid (64 mt, 8 ct, 4 b), 64x64 tiles via LDS.
// ---------------------------------------------------------------------------
__global__ __launch_bounds__(256) void hnT_k(
    const float* __restrict__ x, const float* __restrict__ gamma,
    const float* __restrict__ beta, const float* __restrict__ stats,
    ushort* __restrict__ hnT) {
    int bm = blockIdx.x * 64, c0 = blockIdx.y * 64, b = blockIdx.z;
    __shared__ ushort Ls[64][65];
    int t = threadIdx.x, tx = t & 15, ty = t >> 4;
    const float* xb = x + ((size_t)b * CH + c0) * NPOS + bm;
#pragma unroll
    for (int it = 0; it < 4; ++it) {
        int cc = ty + it * 16;
        int ch = c0 + cc;
        int bg = b * NGRP + (ch >> 4);
        float ga = stats[128 + bg] * gamma[ch];
        float be = beta[ch] - stats[bg] * ga;
        float4 v = *(const float4*)(xb + (size_t)cc * NPOS + tx * 4);
        Ls[cc][tx * 4 + 0] = f2b(v.x * ga + be);
        Ls[cc][tx * 4 + 1] = f2b(v.y * ga + be);
        Ls[cc][tx * 4 + 2] = f2b(v.z * ga + be);
        Ls[cc][tx * 4 + 3] = f2b(v.w * ga + be);
    }
    __syncthreads();
#pragma unroll
    for (int it = 0; it < 4; ++it) {
        int mm = ty + it * 16;
        ushort4 o;
        o.x = Ls[tx * 4 + 0][mm];
        o.y = Ls[tx * 4 + 1][mm];
        o.z = Ls[tx * 4 + 2][mm];
        o.w = Ls[tx * 4 + 3][mm];
        *(ushort4*)(hnT + ((size_t)(b * NPOS) + bm + mm) * CH + c0 + tx * 4) = o;
    }
}

// ---------------------------------------------------------------------------
// K3: QKV GEMM on MFMA, no LDS. grid (64 mt, 8 ot, 4 b), 4 waves; wave tile
// 32m x 32o, all 3 outputs. Same regs serve A (rows) for q/k, B (cols) for v.
// Outputs: qT[b][m][o] (pre-scaled), kT[b][m][o], vB[b][o][m].
// ---------------------------------------------------------------------------
__global__ __launch_bounds__(256) void qkv3_k(
    const ushort* __restrict__ hnT, const ushort* __restrict__ W4,
    const float* __restrict__ bq, const float* __restrict__ bk,
    const float* __restrict__ bv,
    ushort* __restrict__ qT, ushort* __restrict__ kT, ushort* __restrict__ vB) {
    int bm = blockIdx.x * 64, bo = blockIdx.y * 64, b = blockIdx.z;
    int t = threadIdx.x, l = t & 63, w = t >> 6;
    int wr = w & 1, wc = w >> 1;
    int lr = l & 15, lg = l >> 4;

    const ushort* ha  = hnT + ((size_t)(b * NPOS) + bm + wr * 32 + lr) * CH + lg * 8;
    const ushort* wqp = W4 + (size_t)(bo + wc * 32 + lr) * CH + lg * 8;
    const ushort* wkp = wqp + WSZ;
    const ushort* wvp = wkp + WSZ;

    f32x4 aq[2][2], ak[2][2], av[2][2];
#pragma unroll
    for (int i = 0; i < 2; ++i)
#pragma unroll
        for (int j = 0; j < 2; ++j) {
            aq[i][j] = (f32x4){0.f, 0.f, 0.f, 0.f};
            ak[i][j] = (f32x4){0.f, 0.f, 0.f, 0.f};
            av[i][j] = (f32x4){0.f, 0.f, 0.f, 0.f};
        }
#pragma unroll
    for (int c0 = 0; c0 < CH; c0 += 32) {
        bf16x8 a0 = *(const bf16x8*)(ha + c0);
        bf16x8 a1 = *(const bf16x8*)(ha + 16 * CH + c0);
        bf16x8 q0 = *(const bf16x8*)(wqp + c0);
        bf16x8 q1 = *(const bf16x8*)(wqp + 16 * CH + c0);
        bf16x8 k0 = *(const bf16x8*)(wkp + c0);
        bf16x8 k1 = *(const bf16x8*)(wkp + 16 * CH + c0);
        bf16x8 v0 = *(const bf16x8*)(wvp + c0);
        bf16x8 v1 = *(const bf16x8*)(wvp + 16 * CH + c0);
        aq[0][0] = __builtin_amdgcn_mfma_f32_16x16x32_bf16(a0, q0, aq[0][0], 0, 0, 0);
        aq[0][1] = __builtin_amdgcn_mfma_f32_16x16x32_bf16(a0, q1, aq[0][1], 0, 0, 0);
        aq[1][0] = __builtin_amdgcn_mfma_f32_16x16x32_bf16(a1, q0, aq[1][0], 0, 0, 0);
        aq[1][1] = __builtin_amdgcn_mfma_f32_16x16x32_bf16(a1, q1, aq[1][1], 0, 0, 0);
        ak[0][0] = __builtin_amdgcn_mfma_f32_16x16x32_bf16(a0, k0, ak[0][0], 0, 0, 0);
        ak[0][1] = __builtin_amdgcn_mfma_f32_16x16x32_bf16(a0, k1, ak[0][1], 0, 0, 0);
        ak[1][0] = __builtin_amdgcn_mfma_f32_16x16x32_bf16(a1, k0, ak[1][0], 0, 0, 0);
        ak[1][1] = __builtin_amdgcn_mfma_f32_16x16x32_bf16(a1, k1, ak[1][1], 0, 0, 0);
        av[0][0] = __builtin_amdgcn_mfma_f32_16x16x32_bf16(v0, a0, av[0][0], 0, 0, 0);
        av[0][1] = __builtin_amdgcn_mfma_f32_16x16x32_bf16(v0, a1, av[0][1], 0, 0, 0);
        av[1][0] = __builtin_amdgcn_mfma_f32_16x16x32_bf16(v1, a0, av[1][0], 0, 0, 0);
        av[1][1] = __builtin_amdgcn_mfma_f32_16x16x32_bf16(v1, a1, av[1][1], 0, 0, 0);
    }
    const float sc = 0.044194173824159216f;   // 512^-0.5 folded into q
#pragma unroll
    for (int j = 0; j < 2; ++j) {
        int o = bo + wc * 32 + j * 16 + lr;
        float bqv = bq[o], bkv = bk[o];
#pragma unroll
        for (int i = 0; i < 2; ++i)
#pragma unroll
            for (int r = 0; r < 4; ++r) {
                int m = bm + wr * 32 + i * 16 + 4 * lg + r;
                size_t base = ((size_t)(b * NPOS) + m) * CH + o;
                qT[base] = f2b((aq[i][j][r] + bqv) * sc);
                kT[base] = f2b(ak[i][j][r] + bkv);
            }
    }
#pragma unroll
    for (int i = 0; i < 2; ++i)
#pragma unroll
        for (int r = 0; r < 4; ++r) {
            int o = bo + wc * 32 + i * 16 + 4 * lg + r;
            float bvv = bv[o];
#pragma unroll
            for (int j = 0; j < 2; ++j) {
                int m = bm + wr * 32 + j * 16 + lr;
                vB[((size_t)(b * CH) + o) * NPOS + m] = f2b(av[i][j][r] + bvv);
            }
        }
}

// ---------------------------------------------------------------------------
// K4: flash attention v6. 512 blocks x 512 threads (8 waves), M_BLK=32.
// Wave w: mi=w&1 (16 rows), ci=w>>1 (c-quarter for both Q-split and PV).
// QK: each wave computes PARTIAL scores over its 128-c slice (qf[4]=16 VGPR,
// 8 MFMA); partials summed via padded LDS exchange Sx[4][32][33] f32.
// Softmax wave-local after the sum (redundant VALU across ci, no extra MFMA).
// PV: c-quarter (acc[8]=32 VGPR), V fragments DIRECT from global L2 (vB is
// 4 MB/batch, XCD-clustered). K tile [32][512] LDS single-buffer, staged via
// global_load_lds; reads finish before b1, stage issued after b1 lands by b2.
// 2 barriers/iter. Defer-max (T13). ~90 VGPR, ~53 KB LDS -> 2-3 blocks/CU.
// ---------------------------------------------------------------------------
__global__ __launch_bounds__(512, 4) void attn_k(
    const ushort* __restrict__ qT, const ushort* __restrict__ kT,
    const ushort* __restrict__ vB, ushort* __restrict__ aoT) {
    __shared__ ushort Ks[32 * 512];        // 32 KB, chunk-swizzled rows
    __shared__ float Sx[4][32][33];        // 16.9 KB partial-score exchange
    __shared__ ushort P_lds[32 * 40];      // 2.5 KB, 80B rows

    // XCD batch clustering: id%8 -> XCD; pairs of XCDs share one batch.
    int id = blockIdx.x;
    int b  = (id & 7) >> 1;
    int mt = ((id >> 3) << 1) | (id & 1);   // 0..127
    int m0 = mt * 32;

    int t = threadIdx.x, l = t & 63, w = t >> 6;   // w 0..7
    int mi = w & 1, ci = w >> 1;                   // ci 0..3
    int lr = l & 15, lg = l >> 4;

    const ushort* kTb = kT + (size_t)b * NPOS * CH;
    const ushort* vBb = vB + (size_t)b * CH * NPOS;

    auto stageK = [&](int n0) {
#pragma unroll
        for (int i = 0; i < 4; ++i) {
            int n = w * 4 + i;
            const ushort* g = kTb + (size_t)(n0 + n) * CH + (l ^ (n & 7)) * 8;
            gld16(&Ks[n * 512], g);
        }
    };

    stageK(0);

    // Q fragments: wave's 16 rows (mi half), c-quarter ci (128 channels).
    const ushort* qrow = qT + ((size_t)(b * NPOS + m0 + mi * 16 + lr)) * CH
                            + ci * 128 + lg * 8;
    bf16x8 qf[4];
#pragma unroll
    for (int ks = 0; ks < 4; ++ks) qf[ks] = *(const bf16x8*)(qrow + ks * 32);

    f32x4 acc[8];
#pragma unroll
    for (int i = 0; i < 8; ++i) acc[i] = (f32x4){0.f, 0.f, 0.f, 0.f};
    float m_run[4], l_run[4];
#pragma unroll
    for (int r = 0; r < 4; ++r) { m_run[r] = -1e30f; l_run[r] = 0.f; }
    __syncthreads();   // prologue: K(0) landed (vmcnt drains at barrier)

    int zk = lr & 7;
    for (int nt = 0; nt < 128; ++nt) {
        int n0 = nt * 32;
        // ---- partial scores over this wave's 128-c slice: S_part[16][32] ----
        f32x4 s0 = {0.f, 0.f, 0.f, 0.f}, s1 = s0;
        const ushort* krow0 = &Ks[(size_t)lr * 512];         // keys 0..15
        const ushort* krow1 = &Ks[(size_t)(16 + lr) * 512];  // keys 16..31
#pragma unroll
        for (int ks = 0; ks < 4; ++ks) {
            int ch = (ci * 16 + ks * 4 + lg) ^ zk;
            bf16x8 kf0 = *(const bf16x8*)(krow0 + ch * 8);
            bf16x8 kf1 = *(const bf16x8*)(krow1 + ch * 8);
            s0 = __builtin_amdgcn_mfma_f32_16x16x32_bf16(qf[ks], kf0, s0, 0, 0, 0);
            s1 = __builtin_amdgcn_mfma_f32_16x16x32_bf16(qf[ks], kf1, s1, 0, 0, 0);
        }
        // write partials: Sx[ci][m][n] (pad 33 -> <=2-way banks)
#pragma unroll
        for (int r = 0; r < 4; ++r) {
            int m = mi * 16 + 4 * lg + r;
            Sx[ci][m][lr]      = s0[r];
            Sx[ci][m][16 + lr] = s1[r];
        }
        __syncthreads();                  // b1: partials ready; Ks reads done
        if (nt + 1 < 128) stageK((nt + 1) * 32);   // lands by b2
        // ---- sum partials -> full S[16][32] for this wave's rows ----
        float s0f[4], s1f[4];
#pragma unroll
        for (int r = 0; r < 4; ++r) {
            int m = mi * 16 + 4 * lg + r;
            s0f[r] = (Sx[0][m][lr] + Sx[1][m][lr])
                   + (Sx[2][m][lr] + Sx[3][m][lr]);
            s1f[r] = (Sx[0][m][16 + lr] + Sx[1][m][16 + lr])
                   + (Sx[2][m][16 + lr] + Sx[3][m][16 + lr]);
        }
        // ---- wave-local softmax over 32 keys (reduce across 16 lr lanes) ----
        float pm[4];
#pragma unroll
        for (int r = 0; r < 4; ++r) pm[r] = fmaxf(s0f[r], s1f[r]);
#pragma unroll
        for (int off = 1; off < 16; off <<= 1)
#pragma unroll
            for (int r = 0; r < 4; ++r) pm[r] = fmaxf(pm[r], __shfl_xor(pm[r], off));
        // defer-max: skip rescale when growth small (P bounded by e^8)
        float growth = fmaxf(fmaxf(pm[0] - m_run[0], pm[1] - m_run[1]),
                             fmaxf(pm[2] - m_run[2], pm[3] - m_run[3]));
        bool resc = !__all(growth <= 8.0f);
        if (resc) {
            float alpha[4];
#pragma unroll
            for (int r = 0; r < 4; ++r) {
                float mnew = fmaxf(m_run[r], pm[r]);
                alpha[r] = __expf(m_run[r] - mnew);
                m_run[r] = mnew;
                l_run[r] *= alpha[r];
            }
#pragma unroll
            for (int cs = 0; cs < 8; ++cs) {
                acc[cs][0] *= alpha[0]; acc[cs][1] *= alpha[1];
                acc[cs][2] *= alpha[2]; acc[cs][3] *= alpha[3];
            }
        }
        float p0[4], p1[4], ps[4];
#pragma unroll
        for (int r = 0; r < 4; ++r) {
            p0[r] = __expf(s0f[r] - m_run[r]);
            p1[r] = __expf(s1f[r] - m_run[r]);
            ps[r] = p0[r] + p1[r];
        }
#pragma unroll
        for (int off = 1; off < 16; off <<= 1)
#pragma unroll
            for (int r = 0; r < 4; ++r) ps[r] += __shfl_xor(ps[r], off);
#pragma unroll
        for (int r = 0; r < 4; ++r) l_run[r] += ps[r];
        // P -> LDS [32][40] (waves with same mi write identical values: benign)
        if (ci == (lg & 1) * 2 + (lr >> 3)) {   // spread redundant writes: only 1 of 4 ci writes
#pragma unroll
            for (int r = 0; r < 4; ++r) {
                int m = mi * 16 + 4 * lg + r;
                P_lds[m * 40 + lr]      = f2b(p0[r]);
                P_lds[m * 40 + 16 + lr] = f2b(p1[r]);
            }
        }
        __syncthreads();                  // b2: P ready; K(t+1) landed
        // ---- PV: O[16 rows][128 c-quarter] += P[16][32] . V(global L2) ----
        bf16x8 pa = *(const bf16x8*)&P_lds[(mi * 16 + lr) * 40 + lg * 8];
        const ushort* v0 = vBb + (size_t)(ci * 128 + lr) * NPOS + n0 + lg * 8;
#pragma unroll
        for (int cs = 0; cs < 8; ++cs) {
            bf16x8 vf = *(const bf16x8*)(v0 + (size_t)cs * 16 * NPOS);
            acc[cs] = __builtin_amdgcn_mfma_f32_16x16x32_bf16(pa, vf, acc[cs], 0, 0, 0);
        }
    }
    // epilogue: normalize, store bf16 aoT[b][m][c]
    float inv[4];
#pragma unroll
    for (int r = 0; r < 4; ++r) inv[r] = 1.0f / l_run[r];
#pragma unroll
    for (int cs = 0; cs < 8; ++cs)
#pragma unroll
        for (int r = 0; r < 4; ++r)
            aoT[((size_t)(b * NPOS + m0 + mi * 16 + 4 * lg + r)) * CH
                + ci * 128 + cs * 16 + lr] = f2b(acc[cs][r] * inv[r]);
}

// ---------------------------------------------------------------------------
// K5: proj on MFMA + bias + residual. A=Wp (rows o), B=aoT bf16 (cols m).
// grid (64 mt, 8 ot, 4 b), 4 waves, wave tile 32o x 32m. No LDS.
// ---------------------------------------------------------------------------
__global__ __launch_bounds__(256) void proj_k(
    const ushort* __restrict__ aoT, const ushort* __restrict__ W4,
    const float* __restrict__ bp, const float* __restrict__ x,
    float* __restrict__ out) {
    int bm = blockIdx.x * 64, bo = blockIdx.y * 64, b = blockIdx.z;
    int t = threadIdx.x, l = t & 63, w = t >> 6;
    int orh = w & 1, mc = w >> 1;
    int lr = l & 15, lg = l >> 4;

    const ushort* wp = W4 + 3 * (size_t)WSZ + (size_t)(bo + orh * 32 + lr) * CH + lg * 8;
    const ushort* ab = aoT + ((size_t)(b * NPOS) + bm + mc * 32 + lr) * CH + lg * 8;

    f32x4 ac[2][2];
#pragma unroll
    for (int i = 0; i < 2; ++i)
#pragma unroll
        for (int j = 0; j < 2; ++j) ac[i][j] = (f32x4){0.f, 0.f, 0.f, 0.f};
#pragma unroll
    for (int c0 = 0; c0 < CH; c0 += 32) {
        bf16x8 w0 = *(const bf16x8*)(wp + c0);
        bf16x8 w1 = *(const bf16x8*)(wp + 16 * CH + c0);
        bf16x8 b0 = *(const bf16x8*)(ab + c0);
        bf16x8 b1 = *(const bf16x8*)(ab + 16 * CH + c0);
        ac[0][0] = __builtin_amdgcn_mfma_f32_16x16x32_bf16(w0, b0, ac[0][0], 0, 0, 0);
        ac[0][1] = __builtin_amdgcn_mfma_f32_16x16x32_bf16(w0, b1, ac[0][1], 0, 0, 0);
        ac[1][0] = __builtin_amdgcn_mfma_f32_16x16x32_bf16(w1, b0, ac[1][0], 0, 0, 0);
        ac[1][1] = __builtin_amdgcn_mfma_f32_16x16x32_bf16(w1, b1, ac[1][1], 0, 0, 0);
    }
#pragma unroll
    for (int i = 0; i < 2; ++i)
#pragma unroll
        for (int r = 0; r < 4; ++r) {
            int o = bo + orh * 32 + i * 16 + 4 * lg + r;
            float bpv = bp[o];
#pragma unroll
            for (int j = 0; j < 2; ++j) {
                int m = bm + mc * 32 + j * 16 + lr;
                size_t base = ((size_t)(b * CH) + o) * NPOS + m;
                out[base] = ac[i][j][r] + bpv + x[base];
            }
        }
}

// ---------------------------------------------------------------------------
extern "C" void kernel_launch(void* const* d_in, const int* in_sizes, int n_in,
                              void* d_out, int out_size, void* d_ws, size_t ws_size,
                              hipStream_t stream) {
    const float* x     = (const float*)d_in[0];
    const float* gamma = (const float*)d_in[1];
    const float* beta  = (const float*)d_in[2];
    const float* Wq    = (const float*)d_in[3];
    const float* bq    = (const float*)d_in[4];
    const float* Wk    = (const float*)d_in[5];
    const float* bk    = (const float*)d_in[6];
    const float* Wv    = (const float*)d_in[7];
    const float* bv    = (const float*)d_in[8];
    const float* Wp    = (const float*)d_in[9];
    const float* bp    = (const float*)d_in[10];
    float* out = (float*)d_out;

    const size_t SZ = (size_t)BATCH * CH * NPOS;               // 8,388,608
    const size_t need = (5 * SZ + 4 * WSZ) * 2 + 1024;         // ~86 MB
    if (ws_size < need) return;

    ushort* qT  = (ushort*)d_ws;          // [b][m][o] bf16 (pre-scaled)
    ushort* kT  = qT + SZ;                // [b][m][o] bf16
    ushort* vb  = kT + SZ;                // [b][o][m] bf16
    ushort* hnT = vb + SZ;                // [b][m][c] bf16
    ushort* aoT = hnT + SZ;               // [b][m][c] bf16
    ushort* W4  = aoT + SZ;               // [4][512][512] bf16
    float*  stats = (float*)(W4 + 4 * (size_t)WSZ);

    gn_stats_k<<<128, 256, 0, stream>>>(x, stats);
    wcvt_k<<<512, 256, 0, stream>>>(Wq, Wk, Wv, Wp, W4);
    hnT_k<<<dim3(64, 8, 4), 256, 0, stream>>>(x, gamma, beta, stats, hnT);
    qkv3_k<<<dim3(64, 8, 4), 256, 0, stream>>>(hnT, W4, bq, bk, bv, qT, kT, vb);
    attn_k<<<dim3(512), 512, 0, stream>>>(qT, kT, vb, aoT);
    proj_k<<<dim3(64, 8, 4), 256, 0, stream>>>(aoT, W4, bp, x, out);
}

// Round 14
// 500.052 us; speedup vs baseline: 1.6906x; 1.6906x over previous
//
#include <hip/hip_runtime.h>
#include <math.h>

// AttnBlock: GroupNorm -> QKV 1x1 conv -> spatial self-attention -> proj 1x1 conv + residual
// x (4, 512, 64, 64) fp32. B=4, C=512, N=HW=4096, 32 groups of 16 ch.
// Round 14: identical to round 13 (bench infra failure — resubmit).
// r10 structure + (1) amdgpu_waves_per_eu(2,2) to stop Q-fragment remat,
// (2) counted-wait raw-barrier pipeline (stage(t+1) issued after top-of-iter
// vmcnt(0) drain of stage(t): full-iteration cover), (3) deferred-l + defer-max.

#define BATCH 4
#define CH    512
#define NPOS  4096
#define NGRP  32
#define GSIZE (16 * NPOS)
#define WSZ   262144   // 512*512

typedef __attribute__((ext_vector_type(8))) short bf16x8;
typedef __attribute__((ext_vector_type(4))) float f32x4;

__device__ __forceinline__ ushort f2b(float x) {   // fp32 -> bf16 RNE
    uint u = __float_as_uint(x);
    u += 0x7fff + ((u >> 16) & 1);
    return (ushort)(u >> 16);
}

// async global->LDS, 16B per lane (lds base wave-uniform, HW adds lane*16)
__device__ __forceinline__ void gld16(void* lds, const void* g) {
    __builtin_amdgcn_global_load_lds(
        (const __attribute__((address_space(1))) void*)g,
        (__attribute__((address_space(3))) void*)lds, 16, 0, 0);
}

// ---------------------------------------------------------------------------
// K1: GroupNorm statistics. One block per (b, g) contiguous 65536-float segment.
// ---------------------------------------------------------------------------
__global__ __launch_bounds__(256) void gn_stats_k(const float* __restrict__ x,
                                                  float* __restrict__ stats) {
    int bg = blockIdx.x;
    const float4* xp = reinterpret_cast<const float4*>(x + (size_t)bg * GSIZE);
    float s1 = 0.f, s2 = 0.f;
    for (int i = threadIdx.x; i < GSIZE / 4; i += 256) {
        float4 v = xp[i];
        s1 += v.x + v.y + v.z + v.w;
        s2 += v.x * v.x + v.y * v.y + v.z * v.z + v.w * v.w;
    }
    for (int off = 32; off > 0; off >>= 1) {
        s1 += __shfl_down(s1, off);
        s2 += __shfl_down(s2, off);
    }
    __shared__ float r1[4], r2[4];
    int wid = threadIdx.x >> 6;
    if ((threadIdx.x & 63) == 0) { r1[wid] = s1; r2[wid] = s2; }
    __syncthreads();
    if (threadIdx.x == 0) {
        float t1 = r1[0] + r1[1] + r1[2] + r1[3];
        float t2 = r2[0] + r2[1] + r2[2] + r2[3];
        float mean = t1 / (float)GSIZE;
        float var  = t2 / (float)GSIZE - mean * mean;
        stats[bg]       = mean;
        stats[128 + bg] = rsqrtf(var + 1e-6f);
    }
}

// ---------------------------------------------------------------------------
// K2a: weights fp32 -> bf16, W4[sel][o][c], sel = q,k,v,p.
// ---------------------------------------------------------------------------
__global__ __launch_bounds__(256) void wcvt_k(
    const float* __restrict__ Wq, const float* __restrict__ Wk,
    const float* __restrict__ Wv, const float* __restrict__ Wp,
    ushort* __restrict__ W4) {
    int id = blockIdx.x;             // 512 blocks
    int sel = id >> 7, blk = id & 127;
    const float* src = sel == 0 ? Wq : (sel == 1 ? Wk : (sel == 2 ? Wv : Wp));
    const float4* s4 = (const float4*)(src + (size_t)blk * 2048);
    ushort4* d4 = (ushort4*)(W4 + (size_t)sel * WSZ + (size_t)blk * 2048);
    for (int i = threadIdx.x; i < 512; i += 256) {
        float4 v = s4[i];
        d4[i] = make_ushort4(f2b(v.x), f2b(v.y), f2b(v.z), f2b(v.w));
    }
}

// ---------------------------------------------------------------------------
// K2b: GroupNorm apply + transpose: x[b][c][m] fp32 -> hnT[b][m][c] bf16.
// grid (64 mt, 8 ct, 4 b), 64x64 tiles via LDS.
// ---------------------------------------------------------------------------
__global__ __launch_bounds__(256) void hnT_k(
    const float* __restrict__ x, const float* __restrict__ gamma,
    const float* __restrict__ beta, const float* __restrict__ stats,
    ushort* __restrict__ hnT) {
    int bm = blockIdx.x * 64, c0 = blockIdx.y * 64, b = blockIdx.z;
    __shared__ ushort Ls[64][65];
    int t = threadIdx.x, tx = t & 15, ty = t >> 4;
    const float* xb = x + ((size_t)b * CH + c0) * NPOS + bm;
#pragma unroll
    for (int it = 0; it < 4; ++it) {
        int cc = ty + it * 16;
        int ch = c0 + cc;
        int bg = b * NGRP + (ch >> 4);
        float ga = stats[128 + bg] * gamma[ch];
        float be = beta[ch] - stats[bg] * ga;
        float4 v = *(const float4*)(xb + (size_t)cc * NPOS + tx * 4);
        Ls[cc][tx * 4 + 0] = f2b(v.x * ga + be);
        Ls[cc][tx * 4 + 1] = f2b(v.y * ga + be);
        Ls[cc][tx * 4 + 2] = f2b(v.z * ga + be);
        Ls[cc][tx * 4 + 3] = f2b(v.w * ga + be);
    }
    __syncthreads();
#pragma unroll
    for (int it = 0; it < 4; ++it) {
        int mm = ty + it * 16;
        ushort4 o;
        o.x = Ls[tx * 4 + 0][mm];
        o.y = Ls[tx * 4 + 1][mm];
        o.z = Ls[tx * 4 + 2][mm];
        o.w = Ls[tx * 4 + 3][mm];
        *(ushort4*)(hnT + ((size_t)(b * NPOS) + bm + mm) * CH + c0 + tx * 4) = o;
    }
}

// ---------------------------------------------------------------------------
// K3: QKV GEMM on MFMA, no LDS. grid (64 mt, 8 ot, 4 b), 4 waves; wave tile
// 32m x 32o, all 3 outputs. Same regs serve A (rows) for q/k, B (cols) for v.
// Outputs: qT[b][m][o] (pre-scaled), kT[b][m][o], vB[b][o][m].
// ---------------------------------------------------------------------------
__global__ __launch_bounds__(256) void qkv3_k(
    const ushort* __restrict__ hnT, const ushort* __restrict__ W4,
    const float* __restrict__ bq, const float* __restrict__ bk,
    const float* __restrict__ bv,
    ushort* __restrict__ qT, ushort* __restrict__ kT, ushort* __restrict__ vB) {
    int bm = blockIdx.x * 64, bo = blockIdx.y * 64, b = blockIdx.z;
    int t = threadIdx.x, l = t & 63, w = t >> 6;
    int wr = w & 1, wc = w >> 1;
    int lr = l & 15, lg = l >> 4;

    const ushort* ha  = hnT + ((size_t)(b * NPOS) + bm + wr * 32 + lr) * CH + lg * 8;
    const ushort* wqp = W4 + (size_t)(bo + wc * 32 + lr) * CH + lg * 8;
    const ushort* wkp = wqp + WSZ;
    const ushort* wvp = wkp + WSZ;

    f32x4 aq[2][2], ak[2][2], av[2][2];
#pragma unroll
    for (int i = 0; i < 2; ++i)
#pragma unroll
        for (int j = 0; j < 2; ++j) {
            aq[i][j] = (f32x4){0.f, 0.f, 0.f, 0.f};
            ak[i][j] = (f32x4){0.f, 0.f, 0.f, 0.f};
            av[i][j] = (f32x4){0.f, 0.f, 0.f, 0.f};
        }
#pragma unroll
    for (int c0 = 0; c0 < CH; c0 += 32) {
        bf16x8 a0 = *(const bf16x8*)(ha + c0);
        bf16x8 a1 = *(const bf16x8*)(ha + 16 * CH + c0);
        bf16x8 q0 = *(const bf16x8*)(wqp + c0);
        bf16x8 q1 = *(const bf16x8*)(wqp + 16 * CH + c0);
        bf16x8 k0 = *(const bf16x8*)(wkp + c0);
        bf16x8 k1 = *(const bf16x8*)(wkp + 16 * CH + c0);
        bf16x8 v0 = *(const bf16x8*)(wvp + c0);
        bf16x8 v1 = *(const bf16x8*)(wvp + 16 * CH + c0);
        aq[0][0] = __builtin_amdgcn_mfma_f32_16x16x32_bf16(a0, q0, aq[0][0], 0, 0, 0);
        aq[0][1] = __builtin_amdgcn_mfma_f32_16x16x32_bf16(a0, q1, aq[0][1], 0, 0, 0);
        aq[1][0] = __builtin_amdgcn_mfma_f32_16x16x32_bf16(a1, q0, aq[1][0], 0, 0, 0);
        aq[1][1] = __builtin_amdgcn_mfma_f32_16x16x32_bf16(a1, q1, aq[1][1], 0, 0, 0);
        ak[0][0] = __builtin_amdgcn_mfma_f32_16x16x32_bf16(a0, k0, ak[0][0], 0, 0, 0);
        ak[0][1] = __builtin_amdgcn_mfma_f32_16x16x32_bf16(a0, k1, ak[0][1], 0, 0, 0);
        ak[1][0] = __builtin_amdgcn_mfma_f32_16x16x32_bf16(a1, k0, ak[1][0], 0, 0, 0);
        ak[1][1] = __builtin_amdgcn_mfma_f32_16x16x32_bf16(a1, k1, ak[1][1], 0, 0, 0);
        av[0][0] = __builtin_amdgcn_mfma_f32_16x16x32_bf16(v0, a0, av[0][0], 0, 0, 0);
        av[0][1] = __builtin_amdgcn_mfma_f32_16x16x32_bf16(v0, a1, av[0][1], 0, 0, 0);
        av[1][0] = __builtin_amdgcn_mfma_f32_16x16x32_bf16(v1, a0, av[1][0], 0, 0, 0);
        av[1][1] = __builtin_amdgcn_mfma_f32_16x16x32_bf16(v1, a1, av[1][1], 0, 0, 0);
    }
    const float sc = 0.044194173824159216f;   // 512^-0.5 folded into q
#pragma unroll
    for (int j = 0; j < 2; ++j) {
        int o = bo + wc * 32 + j * 16 + lr;
        float bqv = bq[o], bkv = bk[o];
#pragma unroll
        for (int i = 0; i < 2; ++i)
#pragma unroll
            for (int r = 0; r < 4; ++r) {
                int m = bm + wr * 32 + i * 16 + 4 * lg + r;
                size_t base = ((size_t)(b * NPOS) + m) * CH + o;
                qT[base] = f2b((aq[i][j][r] + bqv) * sc);
                kT[base] = f2b(ak[i][j][r] + bkv);
            }
    }
#pragma unroll
    for (int i = 0; i < 2; ++i)
#pragma unroll
        for (int r = 0; r < 4; ++r) {
            int o = bo + wc * 32 + i * 16 + 4 * lg + r;
            float bvv = bv[o];
#pragma unroll
            for (int j = 0; j < 2; ++j) {
                int m = bm + wr * 32 + j * 16 + lr;
                vB[((size_t)(b * CH) + o) * NPOS + m] = f2b(av[i][j][r] + bvv);
            }
        }
}

// ---------------------------------------------------------------------------
// K4: flash attention v7. 256 blocks x 512 threads (8 waves, 1 block/CU).
// r10 dataflow (verified): wave w: mi=w&3 (16 rows of M_BLK=64), ci=w>>2
// (score n-half / PV c-half). K dbuf + V dbuf + single P + mpart.
// Pipeline (counted-wait, raw barriers):
//   b0: vmcnt(0) [drains stage(t), issued a FULL ITERATION ago] + s_barrier
//   issue stage(t+1) -> alt buffers (stays in flight across b1/b2)
//   QK(t) -> max reduce -> mpart ; lgkmcnt(0)+s_barrier [b1]
//   combined max, defer-max(T13), exp, P write, rescale ; lgkmcnt(0)+s_barrier [b2]
//   PV(t). l-sum DEFERRED: per-lane partials, one exchange after the loop.
// amdgpu_waves_per_eu(2,2): pins allocator to the real occupancy (LDS-capped
// 2 waves/SIMD) so qf[16]+acc[16] stay resident (r8-r11 all remat'd Q at <=128).
// ---------------------------------------------------------------------------
__global__ __launch_bounds__(512) __attribute__((amdgpu_waves_per_eu(2, 2)))
void attn_k(
    const ushort* __restrict__ qT, const ushort* __restrict__ kT,
    const ushort* __restrict__ vB, ushort* __restrict__ aoT) {
    __shared__ ushort Ks[2][32 * 512];     // 64 KB
    __shared__ ushort Vs[2][512 * 32];     // 64 KB
    __shared__ ushort P_lds[64 * 40];      // 5 KB, 80B rows
    __shared__ float mpart[2][4][16];      // [ci][mi][row]

    // XCD batch clustering: id%8 -> XCD; pairs of XCDs share one batch.
    int id = blockIdx.x;
    int b  = (id & 7) >> 1;
    int mt = ((id >> 3) << 1) | (id & 1);   // 0..63
    int m0 = mt * 64;

    int t = threadIdx.x, l = t & 63, w = t >> 6;   // w 0..7
    int mi = w & 3, ci = w >> 2;
    int lr = l & 15, lg = l >> 4;

    const ushort* kTb = kT + (size_t)b * NPOS * CH;
    const ushort* vBb = vB + (size_t)b * CH * NPOS;

    auto stageK = [&](int n0, ushort* kbuf) {
#pragma unroll
        for (int i = 0; i < 4; ++i) {
            int n = w * 4 + i;
            const ushort* g = kTb + (size_t)(n0 + n) * CH + (l ^ (n & 7)) * 8;
            gld16(&kbuf[n * 512], g);
        }
    };
    auto stageV = [&](int n0, ushort* vbuf) {
#pragma unroll
        for (int i = 0; i < 4; ++i) {
            int cb = w * 64 + i * 16;
            int c  = cb + (l >> 2);
            int sc = (l & 3) ^ ((c >> 1) & 3);
            const ushort* g = vBb + (size_t)c * NPOS + n0 + sc * 8;
            gld16(&vbuf[cb * 32], g);
        }
    };

    stageK(0, &Ks[0][0]);
    stageV(0, &Vs[0][0]);

    // Q fragments: wave's 16 rows (mi quarter), full C=512. 64 VGPR, resident.
    const ushort* qrow = qT + ((size_t)(b * NPOS + m0 + mi * 16 + lr)) * CH + lg * 8;
    bf16x8 qf[16];
#pragma unroll
    for (int ks = 0; ks < 16; ++ks) qf[ks] = *(const bf16x8*)(qrow + ks * 32);

    f32x4 acc[16];
#pragma unroll
    for (int i = 0; i < 16; ++i) acc[i] = (f32x4){0.f, 0.f, 0.f, 0.f};
    float m_run[4], lsum[4];
#pragma unroll
    for (int r = 0; r < 4; ++r) { m_run[r] = -1e30f; lsum[r] = 0.f; }

    int zk = lr & 7;
    for (int nt = 0; nt < 128; ++nt) {
        const ushort* ks_cur = &Ks[nt & 1][0];
        const ushort* vs_cur = &Vs[nt & 1][0];
        // b0: stage(t) (issued one full iteration ago) has landed everywhere.
        asm volatile("s_waitcnt vmcnt(0)" ::: "memory");
        __builtin_amdgcn_s_barrier();
        __builtin_amdgcn_sched_barrier(0);
        if (nt + 1 < 128) {   // in flight across b1/b2, drained at next b0
            stageK((nt + 1) * 32, &Ks[(nt + 1) & 1][0]);
            stageV((nt + 1) * 32, &Vs[(nt + 1) & 1][0]);
        }
        // ---- scores: S[16 rows (mi)][16 keys (ci)], 4-way split acc ----
        f32x4 sp0 = {0.f, 0.f, 0.f, 0.f}, sp1 = sp0, sp2 = sp0, sp3 = sp0;
        const ushort* krow = &ks_cur[(ci * 16 + lr) * 512];
#pragma unroll
        for (int ks = 0; ks < 16; ks += 4) {
            bf16x8 kf0 = *(const bf16x8*)(krow + (((ks + 0) * 4 + lg) ^ zk) * 8);
            bf16x8 kf1 = *(const bf16x8*)(krow + (((ks + 1) * 4 + lg) ^ zk) * 8);
            bf16x8 kf2 = *(const bf16x8*)(krow + (((ks + 2) * 4 + lg) ^ zk) * 8);
            bf16x8 kf3 = *(const bf16x8*)(krow + (((ks + 3) * 4 + lg) ^ zk) * 8);
            sp0 = __builtin_amdgcn_mfma_f32_16x16x32_bf16(qf[ks + 0], kf0, sp0, 0, 0, 0);
            sp1 = __builtin_amdgcn_mfma_f32_16x16x32_bf16(qf[ks + 1], kf1, sp1, 0, 0, 0);
            sp2 = __builtin_amdgcn_mfma_f32_16x16x32_bf16(qf[ks + 2], kf2, sp2, 0, 0, 0);
            sp3 = __builtin_amdgcn_mfma_f32_16x16x32_bf16(qf[ks + 3], kf3, sp3, 0, 0, 0);
        }
        f32x4 s = (sp0 + sp1) + (sp2 + sp3);
        // row-max over this wave's 16 keys (reduce over lr)
        float pm[4];
#pragma unroll
        for (int r = 0; r < 4; ++r) pm[r] = s[r];
#pragma unroll
        for (int off = 1; off < 16; off <<= 1)
#pragma unroll
            for (int r = 0; r < 4; ++r) pm[r] = fmaxf(pm[r], __shfl_xor(pm[r], off));
        if (lr == 0) {
#pragma unroll
            for (int r = 0; r < 4; ++r) mpart[ci][mi][4 * lg + r] = pm[r];
        }
        asm volatile("s_waitcnt lgkmcnt(0)" ::: "memory");
        __builtin_amdgcn_s_barrier();                 // b1: mpart visible
        __builtin_amdgcn_sched_barrier(0);
        // combined max + defer-max
        float mt2[4];
        float growth = -1e30f;
#pragma unroll
        for (int r = 0; r < 4; ++r) {
            int row = 4 * lg + r;
            mt2[r] = fmaxf(mpart[0][mi][row], mpart[1][mi][row]);
            growth = fmaxf(growth, mt2[r] - m_run[r]);
        }
        bool resc = !__all(growth <= 8.0f);
        if (resc) {
            float alpha[4];
#pragma unroll
            for (int r = 0; r < 4; ++r) {
                float mnew = fmaxf(m_run[r], mt2[r]);
                alpha[r] = __expf(m_run[r] - mnew);
                m_run[r] = mnew;
                lsum[r] *= alpha[r];
            }
#pragma unroll
            for (int cs = 0; cs < 16; ++cs) {
                acc[cs][0] *= alpha[0]; acc[cs][1] *= alpha[1];
                acc[cs][2] *= alpha[2]; acc[cs][3] *= alpha[3];
            }
        }
        float p[4];
#pragma unroll
        for (int r = 0; r < 4; ++r) {
            p[r] = __expf(s[r] - m_run[r]);
            lsum[r] += p[r];                    // deferred l: per-lane partial
        }
#pragma unroll
        for (int r = 0; r < 4; ++r)
            P_lds[(mi * 16 + 4 * lg + r) * 40 + ci * 16 + lr] = f2b(p[r]);
        asm volatile("s_waitcnt lgkmcnt(0)" ::: "memory");
        __builtin_amdgcn_s_barrier();                 // b2: P visible
        __builtin_amdgcn_sched_barrier(0);
        // ---- PV: O[16 rows][256 c-half] += P[16][32] . V ----
        bf16x8 pa = *(const bf16x8*)&P_lds[(mi * 16 + lr) * 40 + lg * 8];
#pragma unroll
        for (int cs = 0; cs < 16; ++cs) {
            int c = ci * 256 + cs * 16 + lr;
            bf16x8 vf = *(const bf16x8*)&vs_cur[c * 32 + ((lg ^ ((c >> 1) & 3)) * 8)];
            acc[cs] = __builtin_amdgcn_mfma_f32_16x16x32_bf16(pa, vf, acc[cs], 0, 0, 0);
        }
    }
    // ---- final l exchange (once): reduce per-lane partials, sum both ci ----
    float ls[4];
#pragma unroll
    for (int r = 0; r < 4; ++r) ls[r] = lsum[r];
#pragma unroll
    for (int off = 1; off < 16; off <<= 1)
#pragma unroll
        for (int r = 0; r < 4; ++r) ls[r] += __shfl_xor(ls[r], off);
    if (lr == 0) {
#pragma unroll
        for (int r = 0; r < 4; ++r) mpart[ci][mi][4 * lg + r] = ls[r];
    }
    asm volatile("s_waitcnt lgkmcnt(0)" ::: "memory");
    __builtin_amdgcn_s_barrier();
    __builtin_amdgcn_sched_barrier(0);
    float inv[4];
#pragma unroll
    for (int r = 0; r < 4; ++r) {
        int row = 4 * lg + r;
        inv[r] = 1.0f / (mpart[0][mi][row] + mpart[1][mi][row]);
    }
#pragma unroll
    for (int cs = 0; cs < 16; ++cs)
#pragma unroll
        for (int r = 0; r < 4; ++r)
            aoT[((size_t)(b * NPOS + m0 + mi * 16 + 4 * lg + r)) * CH
                + ci * 256 + cs * 16 + lr] = f2b(acc[cs][r] * inv[r]);
}

// ---------------------------------------------------------------------------
// K5: proj on MFMA + bias + residual. A=Wp (rows o), B=aoT bf16 (cols m).
// grid (64 mt, 8 ot, 4 b), 4 waves, wave tile 32o x 32m. No LDS.
// ---------------------------------------------------------------------------
__global__ __launch_bounds__(256) void proj_k(
    const ushort* __restrict__ aoT, const ushort* __restrict__ W4,
    const float* __restrict__ bp, const float* __restrict__ x,
    float* __restrict__ out) {
    int bm = blockIdx.x * 64, bo = blockIdx.y * 64, b = blockIdx.z;
    int t = threadIdx.x, l = t & 63, w = t >> 6;
    int orh = w & 1, mc = w >> 1;
    int lr = l & 15, lg = l >> 4;

    const ushort* wp = W4 + 3 * (size_t)WSZ + (size_t)(bo + orh * 32 + lr) * CH + lg * 8;
    const ushort* ab = aoT + ((size_t)(b * NPOS) + bm + mc * 32 + lr) * CH + lg * 8;

    f32x4 ac[2][2];
#pragma unroll
    for (int i = 0; i < 2; ++i)
#pragma unroll
        for (int j = 0; j < 2; ++j) ac[i][j] = (f32x4){0.f, 0.f, 0.f, 0.f};
#pragma unroll
    for (int c0 = 0; c0 < CH; c0 += 32) {
        bf16x8 w0 = *(const bf16x8*)(wp + c0);
        bf16x8 w1 = *(const bf16x8*)(wp + 16 * CH + c0);
        bf16x8 b0 = *(const bf16x8*)(ab + c0);
        bf16x8 b1 = *(const bf16x8*)(ab + 16 * CH + c0);
        ac[0][0] = __builtin_amdgcn_mfma_f32_16x16x32_bf16(w0, b0, ac[0][0], 0, 0, 0);
        ac[0][1] = __builtin_amdgcn_mfma_f32_16x16x32_bf16(w0, b1, ac[0][1], 0, 0, 0);
        ac[1][0] = __builtin_amdgcn_mfma_f32_16x16x32_bf16(w1, b0, ac[1][0], 0, 0, 0);
        ac[1][1] = __builtin_amdgcn_mfma_f32_16x16x32_bf16(w1, b1, ac[1][1], 0, 0, 0);
    }
#pragma unroll
    for (int i = 0; i < 2; ++i)
#pragma unroll
        for (int r = 0; r < 4; ++r) {
            int o = bo + orh * 32 + i * 16 + 4 * lg + r;
            float bpv = bp[o];
#pragma unroll
            for (int j = 0; j < 2; ++j) {
                int m = bm + mc * 32 + j * 16 + lr;
                size_t base = ((size_t)(b * CH) + o) * NPOS + m;
                out[base] = ac[i][j][r] + bpv + x[base];
            }
        }
}

// ---------------------------------------------------------------------------
extern "C" void kernel_launch(void* const* d_in, const int* in_sizes, int n_in,
                              void* d_out, int out_size, void* d_ws, size_t ws_size,
                              hipStream_t stream) {
    const float* x     = (const float*)d_in[0];
    const float* gamma = (const float*)d_in[1];
    const float* beta  = (const float*)d_in[2];
    const float* Wq    = (const float*)d_in[3];
    const float* bq    = (const float*)d_in[4];
    const float* Wk    = (const float*)d_in[5];
    const float* bk    = (const float*)d_in[6];
    const float* Wv    = (const float*)d_in[7];
    const float* bv    = (const float*)d_in[8];
    const float* Wp    = (const float*)d_in[9];
    const float* bp    = (const float*)d_in[10];
    float* out = (float*)d_out;

    const size_t SZ = (size_t)BATCH * CH * NPOS;               // 8,388,608
    const size_t need = (5 * SZ + 4 * WSZ) * 2 + 1024;         // ~86 MB
    if (ws_size < need) return;

    ushort* qT  = (ushort*)d_ws;          // [b][m][o] bf16 (pre-scaled)
    ushort* kT  = qT + SZ;                // [b][m][o] bf16
    ushort* vb  = kT + SZ;                // [b][o][m] bf16
    ushort* hnT = vb + SZ;                // [b][m][c] bf16
    ushort* aoT = hnT + SZ;               // [b][m][c] bf16
    ushort* W4  = aoT + SZ;               // [4][512][512] bf16
    float*  stats = (float*)(W4 + 4 * (size_t)WSZ);

    gn_stats_k<<<128, 256, 0, stream>>>(x, stats);
    wcvt_k<<<512, 256, 0, stream>>>(Wq, Wk, Wv, Wp, W4);
    hnT_k<<<dim3(64, 8, 4), 256, 0, stream>>>(x, gamma, beta, stats, hnT);
    qkv3_k<<<dim3(64, 8, 4), 256, 0, stream>>>(hnT, W4, bq, bk, bv, qT, kT, vb);
    attn_k<<<dim3(256), 512, 0, stream>>>(qT, kT, vb, aoT);
    proj_k<<<dim3(64, 8, 4), 256, 0, stream>>>(aoT, W4, bp, x, out);
}

// Round 15
// 427.631 us; speedup vs baseline: 1.9770x; 1.1694x over previous
//
#include <hip/hip_runtime.h>
#include <math.h>

// AttnBlock: GroupNorm -> QKV 1x1 conv -> spatial self-attention -> proj 1x1 conv + residual
// x (4, 512, 64, 64) fp32. B=4, C=512, N=HW=4096, 32 groups of 16 ch.
// Round 15: attn v8 — KVBLK=64 (64 iters), K+V single-buffered 64KB tiles,
// never-zero counted vmcnt(8) pipeline, 8-way V chunk swizzle (conflict-free).
// r14 lesson: wins came from stage cover + deferred-l; per-iter fixed costs
// (barriers, addr VALU) and V-read conflicts are the measured remainder.

#define BATCH 4
#define CH    512
#define NPOS  4096
#define NGRP  32
#define GSIZE (16 * NPOS)
#define WSZ   262144   // 512*512
#define KVB   64
#define NT    64       // 4096 / KVB

typedef __attribute__((ext_vector_type(8))) short bf16x8;
typedef __attribute__((ext_vector_type(4))) float f32x4;

__device__ __forceinline__ ushort f2b(float x) {   // fp32 -> bf16 RNE
    uint u = __float_as_uint(x);
    u += 0x7fff + ((u >> 16) & 1);
    return (ushort)(u >> 16);
}

// async global->LDS, 16B per lane (lds base wave-uniform, HW adds lane*16)
__device__ __forceinline__ void gld16(void* lds, const void* g) {
    __builtin_amdgcn_global_load_lds(
        (const __attribute__((address_space(1))) void*)g,
        (__attribute__((address_space(3))) void*)lds, 16, 0, 0);
}

// ---------------------------------------------------------------------------
// K1: GroupNorm statistics. One block per (b, g) contiguous 65536-float segment.
// ---------------------------------------------------------------------------
__global__ __launch_bounds__(256) void gn_stats_k(const float* __restrict__ x,
                                                  float* __restrict__ stats) {
    int bg = blockIdx.x;
    const float4* xp = reinterpret_cast<const float4*>(x + (size_t)bg * GSIZE);
    float s1 = 0.f, s2 = 0.f;
    for (int i = threadIdx.x; i < GSIZE / 4; i += 256) {
        float4 v = xp[i];
        s1 += v.x + v.y + v.z + v.w;
        s2 += v.x * v.x + v.y * v.y + v.z * v.z + v.w * v.w;
    }
    for (int off = 32; off > 0; off >>= 1) {
        s1 += __shfl_down(s1, off);
        s2 += __shfl_down(s2, off);
    }
    __shared__ float r1[4], r2[4];
    int wid = threadIdx.x >> 6;
    if ((threadIdx.x & 63) == 0) { r1[wid] = s1; r2[wid] = s2; }
    __syncthreads();
    if (threadIdx.x == 0) {
        float t1 = r1[0] + r1[1] + r1[2] + r1[3];
        float t2 = r2[0] + r2[1] + r2[2] + r2[3];
        float mean = t1 / (float)GSIZE;
        float var  = t2 / (float)GSIZE - mean * mean;
        stats[bg]       = mean;
        stats[128 + bg] = rsqrtf(var + 1e-6f);
    }
}

// ---------------------------------------------------------------------------
// K2a: weights fp32 -> bf16, W4[sel][o][c], sel = q,k,v,p.
// ---------------------------------------------------------------------------
__global__ __launch_bounds__(256) void wcvt_k(
    const float* __restrict__ Wq, const float* __restrict__ Wk,
    const float* __restrict__ Wv, const float* __restrict__ Wp,
    ushort* __restrict__ W4) {
    int id = blockIdx.x;             // 512 blocks
    int sel = id >> 7, blk = id & 127;
    const float* src = sel == 0 ? Wq : (sel == 1 ? Wk : (sel == 2 ? Wv : Wp));
    const float4* s4 = (const float4*)(src + (size_t)blk * 2048);
    ushort4* d4 = (ushort4*)(W4 + (size_t)sel * WSZ + (size_t)blk * 2048);
    for (int i = threadIdx.x; i < 512; i += 256) {
        float4 v = s4[i];
        d4[i] = make_ushort4(f2b(v.x), f2b(v.y), f2b(v.z), f2b(v.w));
    }
}

// ---------------------------------------------------------------------------
// K2b: GroupNorm apply + transpose: x[b][c][m] fp32 -> hnT[b][m][c] bf16.
// grid (64 mt, 8 ct, 4 b), 64x64 tiles via LDS.
// ---------------------------------------------------------------------------
__global__ __launch_bounds__(256) void hnT_k(
    const float* __restrict__ x, const float* __restrict__ gamma,
    const float* __restrict__ beta, const float* __restrict__ stats,
    ushort* __restrict__ hnT) {
    int bm = blockIdx.x * 64, c0 = blockIdx.y * 64, b = blockIdx.z;
    __shared__ ushort Ls[64][65];
    int t = threadIdx.x, tx = t & 15, ty = t >> 4;
    const float* xb = x + ((size_t)b * CH + c0) * NPOS + bm;
#pragma unroll
    for (int it = 0; it < 4; ++it) {
        int cc = ty + it * 16;
        int ch = c0 + cc;
        int bg = b * NGRP + (ch >> 4);
        float ga = stats[128 + bg] * gamma[ch];
        float be = beta[ch] - stats[bg] * ga;
        float4 v = *(const float4*)(xb + (size_t)cc * NPOS + tx * 4);
        Ls[cc][tx * 4 + 0] = f2b(v.x * ga + be);
        Ls[cc][tx * 4 + 1] = f2b(v.y * ga + be);
        Ls[cc][tx * 4 + 2] = f2b(v.z * ga + be);
        Ls[cc][tx * 4 + 3] = f2b(v.w * ga + be);
    }
    __syncthreads();
#pragma unroll
    for (int it = 0; it < 4; ++it) {
        int mm = ty + it * 16;
        ushort4 o;
        o.x = Ls[tx * 4 + 0][mm];
        o.y = Ls[tx * 4 + 1][mm];
        o.z = Ls[tx * 4 + 2][mm];
        o.w = Ls[tx * 4 + 3][mm];
        *(ushort4*)(hnT + ((size_t)(b * NPOS) + bm + mm) * CH + c0 + tx * 4) = o;
    }
}

// ---------------------------------------------------------------------------
// K3: QKV GEMM on MFMA, no LDS. grid (64 mt, 8 ot, 4 b), 4 waves; wave tile
// 32m x 32o, all 3 outputs. Same regs serve A (rows) for q/k, B (cols) for v.
// Outputs: qT[b][m][o] (pre-scaled), kT[b][m][o], vB[b][o][m].
// ---------------------------------------------------------------------------
__global__ __launch_bounds__(256) void qkv3_k(
    const ushort* __restrict__ hnT, const ushort* __restrict__ W4,
    const float* __restrict__ bq, const float* __restrict__ bk,
    const float* __restrict__ bv,
    ushort* __restrict__ qT, ushort* __restrict__ kT, ushort* __restrict__ vB) {
    int bm = blockIdx.x * 64, bo = blockIdx.y * 64, b = blockIdx.z;
    int t = threadIdx.x, l = t & 63, w = t >> 6;
    int wr = w & 1, wc = w >> 1;
    int lr = l & 15, lg = l >> 4;

    const ushort* ha  = hnT + ((size_t)(b * NPOS) + bm + wr * 32 + lr) * CH + lg * 8;
    const ushort* wqp = W4 + (size_t)(bo + wc * 32 + lr) * CH + lg * 8;
    const ushort* wkp = wqp + WSZ;
    const ushort* wvp = wkp + WSZ;

    f32x4 aq[2][2], ak[2][2], av[2][2];
#pragma unroll
    for (int i = 0; i < 2; ++i)
#pragma unroll
        for (int j = 0; j < 2; ++j) {
            aq[i][j] = (f32x4){0.f, 0.f, 0.f, 0.f};
            ak[i][j] = (f32x4){0.f, 0.f, 0.f, 0.f};
            av[i][j] = (f32x4){0.f, 0.f, 0.f, 0.f};
        }
#pragma unroll
    for (int c0 = 0; c0 < CH; c0 += 32) {
        bf16x8 a0 = *(const bf16x8*)(ha + c0);
        bf16x8 a1 = *(const bf16x8*)(ha + 16 * CH + c0);
        bf16x8 q0 = *(const bf16x8*)(wqp + c0);
        bf16x8 q1 = *(const bf16x8*)(wqp + 16 * CH + c0);
        bf16x8 k0 = *(const bf16x8*)(wkp + c0);
        bf16x8 k1 = *(const bf16x8*)(wkp + 16 * CH + c0);
        bf16x8 v0 = *(const bf16x8*)(wvp + c0);
        bf16x8 v1 = *(const bf16x8*)(wvp + 16 * CH + c0);
        aq[0][0] = __builtin_amdgcn_mfma_f32_16x16x32_bf16(a0, q0, aq[0][0], 0, 0, 0);
        aq[0][1] = __builtin_amdgcn_mfma_f32_16x16x32_bf16(a0, q1, aq[0][1], 0, 0, 0);
        aq[1][0] = __builtin_amdgcn_mfma_f32_16x16x32_bf16(a1, q0, aq[1][0], 0, 0, 0);
        aq[1][1] = __builtin_amdgcn_mfma_f32_16x16x32_bf16(a1, q1, aq[1][1], 0, 0, 0);
        ak[0][0] = __builtin_amdgcn_mfma_f32_16x16x32_bf16(a0, k0, ak[0][0], 0, 0, 0);
        ak[0][1] = __builtin_amdgcn_mfma_f32_16x16x32_bf16(a0, k1, ak[0][1], 0, 0, 0);
        ak[1][0] = __builtin_amdgcn_mfma_f32_16x16x32_bf16(a1, k0, ak[1][0], 0, 0, 0);
        ak[1][1] = __builtin_amdgcn_mfma_f32_16x16x32_bf16(a1, k1, ak[1][1], 0, 0, 0);
        av[0][0] = __builtin_amdgcn_mfma_f32_16x16x32_bf16(v0, a0, av[0][0], 0, 0, 0);
        av[0][1] = __builtin_amdgcn_mfma_f32_16x16x32_bf16(v0, a1, av[0][1], 0, 0, 0);
        av[1][0] = __builtin_amdgcn_mfma_f32_16x16x32_bf16(v1, a0, av[1][0], 0, 0, 0);
        av[1][1] = __builtin_amdgcn_mfma_f32_16x16x32_bf16(v1, a1, av[1][1], 0, 0, 0);
    }
    const float sc = 0.044194173824159216f;   // 512^-0.5 folded into q
#pragma unroll
    for (int j = 0; j < 2; ++j) {
        int o = bo + wc * 32 + j * 16 + lr;
        float bqv = bq[o], bkv = bk[o];
#pragma unroll
        for (int i = 0; i < 2; ++i)
#pragma unroll
            for (int r = 0; r < 4; ++r) {
                int m = bm + wr * 32 + i * 16 + 4 * lg + r;
                size_t base = ((size_t)(b * NPOS) + m) * CH + o;
                qT[base] = f2b((aq[i][j][r] + bqv) * sc);
                kT[base] = f2b(ak[i][j][r] + bkv);
            }
    }
#pragma unroll
    for (int i = 0; i < 2; ++i)
#pragma unroll
        for (int r = 0; r < 4; ++r) {
            int o = bo + wc * 32 + i * 16 + 4 * lg + r;
            float bvv = bv[o];
#pragma unroll
            for (int j = 0; j < 2; ++j) {
                int m = bm + wr * 32 + j * 16 + lr;
                vB[((size_t)(b * CH) + o) * NPOS + m] = f2b(av[i][j][r] + bvv);
            }
        }
}

// ---------------------------------------------------------------------------
// K4: flash attention v8. 256 blocks x 512 threads (8 waves, 1 block/CU).
// Wave w: mi=w&3 (16 rows of M_BLK=64), ci=w>>2 (32-key half for scores,
// 256-c half for PV). KVBLK=64, 64 iterations.
// LDS: Ks[64][512] single (64KB, chunk^=(n&7) swz), Vs[512][64] single
// (64KB, chunk^=(c&7) swz -> conflict-free), P[64 rows][144B stride], mpart.
// Pipeline (counted waits, never vmcnt(0) mid-iter):
//   b0: vmcnt(0) [K(t), cover=softmax+PV(t-1)] + s_barrier [Vs free]
//   issue stageV(t) -> QK(t) -> lgkm+b1 [mpart; Ks reads done]
//   issue stageK(t+1) -> softmax/P/rescale (T13 defer-max, deferred-l)
//   vmcnt(8) [V(t) done; K(t+1) in flight] + lgkm + b2 -> PV(t)
// ---------------------------------------------------------------------------
__global__ __launch_bounds__(512) __attribute__((amdgpu_waves_per_eu(2, 2)))
void attn_k(
    const ushort* __restrict__ qT, const ushort* __restrict__ kT,
    const ushort* __restrict__ vB, ushort* __restrict__ aoT) {
    __shared__ ushort Ks[KVB * 512];       // 64 KB
    __shared__ ushort Vs[512 * KVB];       // 64 KB
    __shared__ ushort P_lds[64 * 72];      // 9 KB, 144B rows
    __shared__ float mpart[2][4][16];      // [ci][mi][row]

    // XCD batch clustering: id%8 -> XCD; pairs of XCDs share one batch.
    int id = blockIdx.x;
    int b  = (id & 7) >> 1;
    int mt = ((id >> 3) << 1) | (id & 1);   // 0..63
    int m0 = mt * 64;

    int t = threadIdx.x, l = t & 63, w = t >> 6;   // w 0..7
    int mi = w & 3, ci = w >> 2;
    int lr = l & 15, lg = l >> 4;

    const ushort* kTb = kT + (size_t)b * NPOS * CH;
    const ushort* vBb = vB + (size_t)b * CH * NPOS;

    // K: 64 rows x 512ch; wave stages 8 rows, 1KB each; chunk^=(n&7) on source.
    auto stageK = [&](int n0) {
#pragma unroll
        for (int i = 0; i < 8; ++i) {
            int n = w * 8 + i;
            const ushort* g = kTb + (size_t)(n0 + n) * CH + (l ^ (n & 7)) * 8;
            gld16(&Ks[n * 512], g);
        }
    };
    // V: 512 rows x 64 keys (128B rows); wave stages 64 rows via 8 gld16
    // (each 1KB = 8 rows); stored chunk j of row c holds source chunk j^(c&7).
    auto stageV = [&](int n0) {
#pragma unroll
        for (int i = 0; i < 8; ++i) {
            int cb = w * 64 + i * 8;
            int c  = cb + (l >> 3);
            int sc = (l & 7) ^ (c & 7);
            const ushort* g = vBb + (size_t)c * NPOS + n0 + sc * 8;
            gld16(&Vs[cb * KVB], g);
        }
    };

    stageK(0);

    // Q fragments: wave's 16 rows (mi quarter), full C=512.
    const ushort* qrow = qT + ((size_t)(b * NPOS + m0 + mi * 16 + lr)) * CH + lg * 8;
    bf16x8 qf[16];
#pragma unroll
    for (int ks = 0; ks < 16; ++ks) qf[ks] = *(const bf16x8*)(qrow + ks * 32);

    f32x4 acc[16];
#pragma unroll
    for (int i = 0; i < 16; ++i) acc[i] = (f32x4){0.f, 0.f, 0.f, 0.f};
    float m_run[4], lsum[4];
#pragma unroll
    for (int r = 0; r < 4; ++r) { m_run[r] = -1e30f; lsum[r] = 0.f; }

    int zk = lr & 7;
    for (int nt = 0; nt < NT; ++nt) {
        int n0 = nt * KVB;
        // b0: K(t) landed (issued at b1 of t-1; cover = softmax+PV).
        asm volatile("s_waitcnt vmcnt(0)" ::: "memory");
        __builtin_amdgcn_s_barrier();                 // all waves done PV(t-1)
        __builtin_amdgcn_sched_barrier(0);
        stageV(n0);                                   // V(t): cover = QK(t)
        // ---- scores: S[16 rows (mi)][32 keys (ci half)], 4-way split ----
        f32x4 s0a = {0.f, 0.f, 0.f, 0.f}, s0b = s0a, s1a = s0a, s1b = s0a;
        const ushort* krow0 = &Ks[(ci * 32 + lr) * 512];
        const ushort* krow1 = &Ks[(ci * 32 + 16 + lr) * 512];
#pragma unroll
        for (int ks = 0; ks < 16; ks += 2) {
            bf16x8 k0a = *(const bf16x8*)(krow0 + (((ks + 0) * 4 + lg) ^ zk) * 8);
            bf16x8 k0b = *(const bf16x8*)(krow0 + (((ks + 1) * 4 + lg) ^ zk) * 8);
            bf16x8 k1a = *(const bf16x8*)(krow1 + (((ks + 0) * 4 + lg) ^ zk) * 8);
            bf16x8 k1b = *(const bf16x8*)(krow1 + (((ks + 1) * 4 + lg) ^ zk) * 8);
            s0a = __builtin_amdgcn_mfma_f32_16x16x32_bf16(qf[ks + 0], k0a, s0a, 0, 0, 0);
            s0b = __builtin_amdgcn_mfma_f32_16x16x32_bf16(qf[ks + 1], k0b, s0b, 0, 0, 0);
            s1a = __builtin_amdgcn_mfma_f32_16x16x32_bf16(qf[ks + 0], k1a, s1a, 0, 0, 0);
            s1b = __builtin_amdgcn_mfma_f32_16x16x32_bf16(qf[ks + 1], k1b, s1b, 0, 0, 0);
        }
        f32x4 s0 = s0a + s0b;    // keys ci*32 + lr-block [0,16)
        f32x4 s1 = s1a + s1b;    // keys ci*32 + 16 + lr-block
        // row-max over this wave's 32 keys (reduce over lr)
        float pm[4];
#pragma unroll
        for (int r = 0; r < 4; ++r) pm[r] = fmaxf(s0[r], s1[r]);
#pragma unroll
        for (int off = 1; off < 16; off <<= 1)
#pragma unroll
            for (int r = 0; r < 4; ++r) pm[r] = fmaxf(pm[r], __shfl_xor(pm[r], off));
        if (lr == 0) {
#pragma unroll
            for (int r = 0; r < 4; ++r) mpart[ci][mi][4 * lg + r] = pm[r];
        }
        asm volatile("s_waitcnt lgkmcnt(0)" ::: "memory");
        __builtin_amdgcn_s_barrier();                 // b1: mpart; Ks reads done
        __builtin_amdgcn_sched_barrier(0);
        if (nt + 1 < NT) stageK((nt + 1) * KVB);      // K(t+1): cover = sm+PV
        // combined max + defer-max (T13)
        float mt2[4];
        float growth = -1e30f;
#pragma unroll
        for (int r = 0; r < 4; ++r) {
            int row = 4 * lg + r;
            mt2[r] = fmaxf(mpart[0][mi][row], mpart[1][mi][row]);
            growth = fmaxf(growth, mt2[r] - m_run[r]);
        }
        bool resc = !__all(growth <= 8.0f);
        if (resc) {
            float alpha[4];
#pragma unroll
            for (int r = 0; r < 4; ++r) {
                float mnew = fmaxf(m_run[r], mt2[r]);
                alpha[r] = __expf(m_run[r] - mnew);
                m_run[r] = mnew;
                lsum[r] *= alpha[r];
            }
#pragma unroll
            for (int cs = 0; cs < 16; ++cs) {
                acc[cs][0] *= alpha[0]; acc[cs][1] *= alpha[1];
                acc[cs][2] *= alpha[2]; acc[cs][3] *= alpha[3];
            }
        }
        float p0[4], p1[4];
#pragma unroll
        for (int r = 0; r < 4; ++r) {
            p0[r] = __expf(s0[r] - m_run[r]);
            p1[r] = __expf(s1[r] - m_run[r]);
            lsum[r] += p0[r] + p1[r];               // deferred l
        }
#pragma unroll
        for (int r = 0; r < 4; ++r) {
            int row = mi * 16 + 4 * lg + r;
            P_lds[row * 72 + ci * 32 + lr]      = f2b(p0[r]);
            P_lds[row * 72 + ci * 32 + 16 + lr] = f2b(p1[r]);
        }
        // b2: V(t) done (8 oldest); K(t+1)'s 8 may stay in flight.
        if (nt + 1 < NT) {
            asm volatile("s_waitcnt vmcnt(8)" ::: "memory");
        } else {
            asm volatile("s_waitcnt vmcnt(0)" ::: "memory");
        }
        asm volatile("s_waitcnt lgkmcnt(0)" ::: "memory");
        __builtin_amdgcn_s_barrier();                 // b2: P visible + V landed
        __builtin_amdgcn_sched_barrier(0);
        // ---- PV: O[16 rows][256 c-half] += P[16][64] . V ----
        bf16x8 pa0 = *(const bf16x8*)&P_lds[(mi * 16 + lr) * 72 + lg * 8];
        bf16x8 pa1 = *(const bf16x8*)&P_lds[(mi * 16 + lr) * 72 + 32 + lg * 8];
#pragma unroll
        for (int cs = 0; cs < 16; ++cs) {
            int c = ci * 256 + cs * 16 + lr;
            bf16x8 vf0 = *(const bf16x8*)&Vs[c * KVB + (((0 * 4 + lg) ^ (c & 7)) * 8)];
            bf16x8 vf1 = *(const bf16x8*)&Vs[c * KVB + (((1 * 4 + lg) ^ (c & 7)) * 8)];
            acc[cs] = __builtin_amdgcn_mfma_f32_16x16x32_bf16(pa0, vf0, acc[cs], 0, 0, 0);
            acc[cs] = __builtin_amdgcn_mfma_f32_16x16x32_bf16(pa1, vf1, acc[cs], 0, 0, 0);
        }
    }
    // ---- final l exchange (once): reduce per-lane partials, sum both ci ----
    float ls[4];
#pragma unroll
    for (int r = 0; r < 4; ++r) ls[r] = lsum[r];
#pragma unroll
    for (int off = 1; off < 16; off <<= 1)
#pragma unroll
        for (int r = 0; r < 4; ++r) ls[r] += __shfl_xor(ls[r], off);
    if (lr == 0) {
#pragma unroll
        for (int r = 0; r < 4; ++r) mpart[ci][mi][4 * lg + r] = ls[r];
    }
    asm volatile("s_waitcnt lgkmcnt(0)" ::: "memory");
    __builtin_amdgcn_s_barrier();
    __builtin_amdgcn_sched_barrier(0);
    float inv[4];
#pragma unroll
    for (int r = 0; r < 4; ++r) {
        int row = 4 * lg + r;
        inv[r] = 1.0f / (mpart[0][mi][row] + mpart[1][mi][row]);
    }
#pragma unroll
    for (int cs = 0; cs < 16; ++cs)
#pragma unroll
        for (int r = 0; r < 4; ++r)
            aoT[((size_t)(b * NPOS + m0 + mi * 16 + 4 * lg + r)) * CH
                + ci * 256 + cs * 16 + lr] = f2b(acc[cs][r] * inv[r]);
}

// ---------------------------------------------------------------------------
// K5: proj on MFMA + bias + residual. A=Wp (rows o), B=aoT bf16 (cols m).
// grid (64 mt, 8 ot, 4 b), 4 waves, wave tile 32o x 32m. No LDS.
// ---------------------------------------------------------------------------
__global__ __launch_bounds__(256) void proj_k(
    const ushort* __restrict__ aoT, const ushort* __restrict__ W4,
    const float* __restrict__ bp, const float* __restrict__ x,
    float* __restrict__ out) {
    int bm = blockIdx.x * 64, bo = blockIdx.y * 64, b = blockIdx.z;
    int t = threadIdx.x, l = t & 63, w = t >> 6;
    int orh = w & 1, mc = w >> 1;
    int lr = l & 15, lg = l >> 4;

    const ushort* wp = W4 + 3 * (size_t)WSZ + (size_t)(bo + orh * 32 + lr) * CH + lg * 8;
    const ushort* ab = aoT + ((size_t)(b * NPOS) + bm + mc * 32 + lr) * CH + lg * 8;

    f32x4 ac[2][2];
#pragma unroll
    for (int i = 0; i < 2; ++i)
#pragma unroll
        for (int j = 0; j < 2; ++j) ac[i][j] = (f32x4){0.f, 0.f, 0.f, 0.f};
#pragma unroll
    for (int c0 = 0; c0 < CH; c0 += 32) {
        bf16x8 w0 = *(const bf16x8*)(wp + c0);
        bf16x8 w1 = *(const bf16x8*)(wp + 16 * CH + c0);
        bf16x8 b0 = *(const bf16x8*)(ab + c0);
        bf16x8 b1 = *(const bf16x8*)(ab + 16 * CH + c0);
        ac[0][0] = __builtin_amdgcn_mfma_f32_16x16x32_bf16(w0, b0, ac[0][0], 0, 0, 0);
        ac[0][1] = __builtin_amdgcn_mfma_f32_16x16x32_bf16(w0, b1, ac[0][1], 0, 0, 0);
        ac[1][0] = __builtin_amdgcn_mfma_f32_16x16x32_bf16(w1, b0, ac[1][0], 0, 0, 0);
        ac[1][1] = __builtin_amdgcn_mfma_f32_16x16x32_bf16(w1, b1, ac[1][1], 0, 0, 0);
    }
#pragma unroll
    for (int i = 0; i < 2; ++i)
#pragma unroll
        for (int r = 0; r < 4; ++r) {
            int o = bo + orh * 32 + i * 16 + 4 * lg + r;
            float bpv = bp[o];
#pragma unroll
            for (int j = 0; j < 2; ++j) {
                int m = bm + mc * 32 + j * 16 + lr;
                size_t base = ((size_t)(b * CH) + o) * NPOS + m;
                out[base] = ac[i][j][r] + bpv + x[base];
            }
        }
}

// ---------------------------------------------------------------------------
extern "C" void kernel_launch(void* const* d_in, const int* in_sizes, int n_in,
                              void* d_out, int out_size, void* d_ws, size_t ws_size,
                              hipStream_t stream) {
    const float* x     = (const float*)d_in[0];
    const float* gamma = (const float*)d_in[1];
    const float* beta  = (const float*)d_in[2];
    const float* Wq    = (const float*)d_in[3];
    const float* bq    = (const float*)d_in[4];
    const float* Wk    = (const float*)d_in[5];
    const float* bk    = (const float*)d_in[6];
    const float* Wv    = (const float*)d_in[7];
    const float* bv    = (const float*)d_in[8];
    const float* Wp    = (const float*)d_in[9];
    const float* bp    = (const float*)d_in[10];
    float* out = (float*)d_out;

    const size_t SZ = (size_t)BATCH * CH * NPOS;               // 8,388,608
    const size_t need = (5 * SZ + 4 * WSZ) * 2 + 1024;         // ~86 MB
    if (ws_size < need) return;

    ushort* qT  = (ushort*)d_ws;          // [b][m][o] bf16 (pre-scaled)
    ushort* kT  = qT + SZ;                // [b][m][o] bf16
    ushort* vb  = kT + SZ;                // [b][o][m] bf16
    ushort* hnT = vb + SZ;                // [b][m][c] bf16
    ushort* aoT = hnT + SZ;               // [b][m][c] bf16
    ushort* W4  = aoT + SZ;               // [4][512][512] bf16
    float*  stats = (float*)(W4 + 4 * (size_t)WSZ);

    gn_stats_k<<<128, 256, 0, stream>>>(x, stats);
    wcvt_k<<<512, 256, 0, stream>>>(Wq, Wk, Wv, Wp, W4);
    hnT_k<<<dim3(64, 8, 4), 256, 0, stream>>>(x, gamma, beta, stats, hnT);
    qkv3_k<<<dim3(64, 8, 4), 256, 0, stream>>>(hnT, W4, bq, bk, bv, qT, kT, vb);
    attn_k<<<dim3(256), 512, 0, stream>>>(qT, kT, vb, aoT);
    proj_k<<<dim3(64, 8, 4), 256, 0, stream>>>(aoT, W4, bp, x, out);
}

// Round 17
// 424.489 us; speedup vs baseline: 1.9916x; 1.0074x over previous
//
#include <hip/hip_runtime.h>
#include <math.h>

// AttnBlock: GroupNorm -> QKV 1x1 conv -> spatial self-attention -> proj 1x1 conv + residual
// x (4, 512, 64, 64) fp32. B=4, C=512, N=HW=4096, 32 groups of 16 ch.
// Round 17: identical to round 16 (bench infra failure — resubmit).
// attn_k byte-identical to r15 (245us). qkv3/proj: depth-1 load pipelines;
// gn_stats+wcvt merged into one launch (independent work, overlapped).

#define BATCH 4
#define CH    512
#define NPOS  4096
#define NGRP  32
#define GSIZE (16 * NPOS)
#define WSZ   262144   // 512*512
#define KVB   64
#define NT    64       // 4096 / KVB

typedef __attribute__((ext_vector_type(8))) short bf16x8;
typedef __attribute__((ext_vector_type(4))) float f32x4;

__device__ __forceinline__ ushort f2b(float x) {   // fp32 -> bf16 RNE
    uint u = __float_as_uint(x);
    u += 0x7fff + ((u >> 16) & 1);
    return (ushort)(u >> 16);
}

// async global->LDS, 16B per lane (lds base wave-uniform, HW adds lane*16)
__device__ __forceinline__ void gld16(void* lds, const void* g) {
    __builtin_amdgcn_global_load_lds(
        (const __attribute__((address_space(1))) void*)g,
        (__attribute__((address_space(3))) void*)lds, 16, 0, 0);
}

// ---------------------------------------------------------------------------
// K1: merged prep — blocks 0..127: GroupNorm stats (one per (b,g) segment);
// blocks 128..639: W fp32->bf16 conversion. Independent work, one launch.
// ---------------------------------------------------------------------------
__global__ __launch_bounds__(256) void prep_k(
    const float* __restrict__ x, float* __restrict__ stats,
    const float* __restrict__ Wq, const float* __restrict__ Wk,
    const float* __restrict__ Wv, const float* __restrict__ Wp,
    ushort* __restrict__ W4) {
    if (blockIdx.x >= 128) {
        int id = blockIdx.x - 128;           // 512 conversion blocks
        int sel = id >> 7, blk = id & 127;
        const float* src = sel == 0 ? Wq : (sel == 1 ? Wk : (sel == 2 ? Wv : Wp));
        const float4* s4 = (const float4*)(src + (size_t)blk * 2048);
        ushort4* d4 = (ushort4*)(W4 + (size_t)sel * WSZ + (size_t)blk * 2048);
        for (int i = threadIdx.x; i < 512; i += 256) {
            float4 v = s4[i];
            d4[i] = make_ushort4(f2b(v.x), f2b(v.y), f2b(v.z), f2b(v.w));
        }
        return;
    }
    int bg = blockIdx.x;
    const float4* xp = reinterpret_cast<const float4*>(x + (size_t)bg * GSIZE);
    float s1 = 0.f, s2 = 0.f;
    for (int i = threadIdx.x; i < GSIZE / 4; i += 256) {
        float4 v = xp[i];
        s1 += v.x + v.y + v.z + v.w;
        s2 += v.x * v.x + v.y * v.y + v.z * v.z + v.w * v.w;
    }
    for (int off = 32; off > 0; off >>= 1) {
        s1 += __shfl_down(s1, off);
        s2 += __shfl_down(s2, off);
    }
    __shared__ float r1[4], r2[4];
    int wid = threadIdx.x >> 6;
    if ((threadIdx.x & 63) == 0) { r1[wid] = s1; r2[wid] = s2; }
    __syncthreads();
    if (threadIdx.x == 0) {
        float t1 = r1[0] + r1[1] + r1[2] + r1[3];
        float t2 = r2[0] + r2[1] + r2[2] + r2[3];
        float mean = t1 / (float)GSIZE;
        float var  = t2 / (float)GSIZE - mean * mean;
        stats[bg]       = mean;
        stats[128 + bg] = rsqrtf(var + 1e-6f);
    }
}

// ---------------------------------------------------------------------------
// K2: GroupNorm apply + transpose: x[b][c][m] fp32 -> hnT[b][m][c] bf16.
// grid (64 mt, 8 ct, 4 b), 64x64 tiles via LDS.
// ---------------------------------------------------------------------------
__global__ __launch_bounds__(256) void hnT_k(
    const float* __restrict__ x, const float* __restrict__ gamma,
    const float* __restrict__ beta, const float* __restrict__ stats,
    ushort* __restrict__ hnT) {
    int bm = blockIdx.x * 64, c0 = blockIdx.y * 64, b = blockIdx.z;
    __shared__ ushort Ls[64][65];
    int t = threadIdx.x, tx = t & 15, ty = t >> 4;
    const float* xb = x + ((size_t)b * CH + c0) * NPOS + bm;
#pragma unroll
    for (int it = 0; it < 4; ++it) {
        int cc = ty + it * 16;
        int ch = c0 + cc;
        int bg = b * NGRP + (ch >> 4);
        float ga = stats[128 + bg] * gamma[ch];
        float be = beta[ch] - stats[bg] * ga;
        float4 v = *(const float4*)(xb + (size_t)cc * NPOS + tx * 4);
        Ls[cc][tx * 4 + 0] = f2b(v.x * ga + be);
        Ls[cc][tx * 4 + 1] = f2b(v.y * ga + be);
        Ls[cc][tx * 4 + 2] = f2b(v.z * ga + be);
        Ls[cc][tx * 4 + 3] = f2b(v.w * ga + be);
    }
    __syncthreads();
#pragma unroll
    for (int it = 0; it < 4; ++it) {
        int mm = ty + it * 16;
        ushort4 o;
        o.x = Ls[tx * 4 + 0][mm];
        o.y = Ls[tx * 4 + 1][mm];
        o.z = Ls[tx * 4 + 2][mm];
        o.w = Ls[tx * 4 + 3][mm];
        *(ushort4*)(hnT + ((size_t)(b * NPOS) + bm + mm) * CH + c0 + tx * 4) = o;
    }
}

// ---------------------------------------------------------------------------
// K3: QKV GEMM on MFMA, no LDS, depth-1 load pipeline (prefetch step s+1's
// 8 fragments before step s's 12 MFMAs). grid (64 mt, 8 ot, 4 b), 4 waves.
// Outputs: qT[b][m][o] (pre-scaled), kT[b][m][o], vB[b][o][m].
// ---------------------------------------------------------------------------
__global__ __launch_bounds__(256) void qkv3_k(
    const ushort* __restrict__ hnT, const ushort* __restrict__ W4,
    const float* __restrict__ bq, const float* __restrict__ bk,
    const float* __restrict__ bv,
    ushort* __restrict__ qT, ushort* __restrict__ kT, ushort* __restrict__ vB) {
    int bm = blockIdx.x * 64, bo = blockIdx.y * 64, b = blockIdx.z;
    int t = threadIdx.x, l = t & 63, w = t >> 6;
    int wr = w & 1, wc = w >> 1;
    int lr = l & 15, lg = l >> 4;

    const ushort* ha  = hnT + ((size_t)(b * NPOS) + bm + wr * 32 + lr) * CH + lg * 8;
    const ushort* wqp = W4 + (size_t)(bo + wc * 32 + lr) * CH + lg * 8;
    const ushort* wkp = wqp + WSZ;
    const ushort* wvp = wkp + WSZ;

    f32x4 aq[2][2], ak[2][2], av[2][2];
#pragma unroll
    for (int i = 0; i < 2; ++i)
#pragma unroll
        for (int j = 0; j < 2; ++j) {
            aq[i][j] = (f32x4){0.f, 0.f, 0.f, 0.f};
            ak[i][j] = (f32x4){0.f, 0.f, 0.f, 0.f};
            av[i][j] = (f32x4){0.f, 0.f, 0.f, 0.f};
        }
    // prologue loads (step 0)
    bf16x8 a0 = *(const bf16x8*)(ha);
    bf16x8 a1 = *(const bf16x8*)(ha + 16 * CH);
    bf16x8 q0 = *(const bf16x8*)(wqp);
    bf16x8 q1 = *(const bf16x8*)(wqp + 16 * CH);
    bf16x8 k0 = *(const bf16x8*)(wkp);
    bf16x8 k1 = *(const bf16x8*)(wkp + 16 * CH);
    bf16x8 v0 = *(const bf16x8*)(wvp);
    bf16x8 v1 = *(const bf16x8*)(wvp + 16 * CH);
#pragma unroll
    for (int s = 0; s < 16; ++s) {
        bf16x8 na0, na1, nq0, nq1, nk0, nk1, nv0, nv1;
        if (s < 15) {                          // prefetch step s+1
            int c1 = (s + 1) * 32;
            na0 = *(const bf16x8*)(ha + c1);
            na1 = *(const bf16x8*)(ha + 16 * CH + c1);
            nq0 = *(const bf16x8*)(wqp + c1);
            nq1 = *(const bf16x8*)(wqp + 16 * CH + c1);
            nk0 = *(const bf16x8*)(wkp + c1);
            nk1 = *(const bf16x8*)(wkp + 16 * CH + c1);
            nv0 = *(const bf16x8*)(wvp + c1);
            nv1 = *(const bf16x8*)(wvp + 16 * CH + c1);
        }
        aq[0][0] = __builtin_amdgcn_mfma_f32_16x16x32_bf16(a0, q0, aq[0][0], 0, 0, 0);
        aq[0][1] = __builtin_amdgcn_mfma_f32_16x16x32_bf16(a0, q1, aq[0][1], 0, 0, 0);
        aq[1][0] = __builtin_amdgcn_mfma_f32_16x16x32_bf16(a1, q0, aq[1][0], 0, 0, 0);
        aq[1][1] = __builtin_amdgcn_mfma_f32_16x16x32_bf16(a1, q1, aq[1][1], 0, 0, 0);
        ak[0][0] = __builtin_amdgcn_mfma_f32_16x16x32_bf16(a0, k0, ak[0][0], 0, 0, 0);
        ak[0][1] = __builtin_amdgcn_mfma_f32_16x16x32_bf16(a0, k1, ak[0][1], 0, 0, 0);
        ak[1][0] = __builtin_amdgcn_mfma_f32_16x16x32_bf16(a1, k0, ak[1][0], 0, 0, 0);
        ak[1][1] = __builtin_amdgcn_mfma_f32_16x16x32_bf16(a1, k1, ak[1][1], 0, 0, 0);
        av[0][0] = __builtin_amdgcn_mfma_f32_16x16x32_bf16(v0, a0, av[0][0], 0, 0, 0);
        av[0][1] = __builtin_amdgcn_mfma_f32_16x16x32_bf16(v0, a1, av[0][1], 0, 0, 0);
        av[1][0] = __builtin_amdgcn_mfma_f32_16x16x32_bf16(v1, a0, av[1][0], 0, 0, 0);
        av[1][1] = __builtin_amdgcn_mfma_f32_16x16x32_bf16(v1, a1, av[1][1], 0, 0, 0);
        if (s < 15) {
            a0 = na0; a1 = na1; q0 = nq0; q1 = nq1;
            k0 = nk0; k1 = nk1; v0 = nv0; v1 = nv1;
        }
    }
    const float sc = 0.044194173824159216f;   // 512^-0.5 folded into q
#pragma unroll
    for (int j = 0; j < 2; ++j) {
        int o = bo + wc * 32 + j * 16 + lr;
        float bqv = bq[o], bkv = bk[o];
#pragma unroll
        for (int i = 0; i < 2; ++i)
#pragma unroll
            for (int r = 0; r < 4; ++r) {
                int m = bm + wr * 32 + i * 16 + 4 * lg + r;
                size_t base = ((size_t)(b * NPOS) + m) * CH + o;
                qT[base] = f2b((aq[i][j][r] + bqv) * sc);
                kT[base] = f2b(ak[i][j][r] + bkv);
            }
    }
#pragma unroll
    for (int i = 0; i < 2; ++i)
#pragma unroll
        for (int r = 0; r < 4; ++r) {
            int o = bo + wc * 32 + i * 16 + 4 * lg + r;
            float bvv = bv[o];
#pragma unroll
            for (int j = 0; j < 2; ++j) {
                int m = bm + wr * 32 + j * 16 + lr;
                vB[((size_t)(b * CH) + o) * NPOS + m] = f2b(av[i][j][r] + bvv);
            }
        }
}

// ---------------------------------------------------------------------------
// K4: flash attention v8 (r15 verified, byte-identical). 256 blocks x 8 waves.
// KVBLK=64, single-buffered K+V 64KB tiles, counted vmcnt(8) pipeline,
// 8-way V chunk swizzle, defer-max (T13), deferred-l.
// ---------------------------------------------------------------------------
__global__ __launch_bounds__(512) __attribute__((amdgpu_waves_per_eu(2, 2)))
void attn_k(
    const ushort* __restrict__ qT, const ushort* __restrict__ kT,
    const ushort* __restrict__ vB, ushort* __restrict__ aoT) {
    __shared__ ushort Ks[KVB * 512];       // 64 KB
    __shared__ ushort Vs[512 * KVB];       // 64 KB
    __shared__ ushort P_lds[64 * 72];      // 9 KB, 144B rows
    __shared__ float mpart[2][4][16];      // [ci][mi][row]

    int id = blockIdx.x;
    int b  = (id & 7) >> 1;
    int mt = ((id >> 3) << 1) | (id & 1);   // 0..63
    int m0 = mt * 64;

    int t = threadIdx.x, l = t & 63, w = t >> 6;   // w 0..7
    int mi = w & 3, ci = w >> 2;
    int lr = l & 15, lg = l >> 4;

    const ushort* kTb = kT + (size_t)b * NPOS * CH;
    const ushort* vBb = vB + (size_t)b * CH * NPOS;

    auto stageK = [&](int n0) {
#pragma unroll
        for (int i = 0; i < 8; ++i) {
            int n = w * 8 + i;
            const ushort* g = kTb + (size_t)(n0 + n) * CH + (l ^ (n & 7)) * 8;
            gld16(&Ks[n * 512], g);
        }
    };
    auto stageV = [&](int n0) {
#pragma unroll
        for (int i = 0; i < 8; ++i) {
            int cb = w * 64 + i * 8;
            int c  = cb + (l >> 3);
            int sc = (l & 7) ^ (c & 7);
            const ushort* g = vBb + (size_t)c * NPOS + n0 + sc * 8;
            gld16(&Vs[cb * KVB], g);
        }
    };

    stageK(0);

    const ushort* qrow = qT + ((size_t)(b * NPOS + m0 + mi * 16 + lr)) * CH + lg * 8;
    bf16x8 qf[16];
#pragma unroll
    for (int ks = 0; ks < 16; ++ks) qf[ks] = *(const bf16x8*)(qrow + ks * 32);

    f32x4 acc[16];
#pragma unroll
    for (int i = 0; i < 16; ++i) acc[i] = (f32x4){0.f, 0.f, 0.f, 0.f};
    float m_run[4], lsum[4];
#pragma unroll
    for (int r = 0; r < 4; ++r) { m_run[r] = -1e30f; lsum[r] = 0.f; }

    int zk = lr & 7;
    for (int nt = 0; nt < NT; ++nt) {
        int n0 = nt * KVB;
        asm volatile("s_waitcnt vmcnt(0)" ::: "memory");
        __builtin_amdgcn_s_barrier();
        __builtin_amdgcn_sched_barrier(0);
        stageV(n0);
        f32x4 s0a = {0.f, 0.f, 0.f, 0.f}, s0b = s0a, s1a = s0a, s1b = s0a;
        const ushort* krow0 = &Ks[(ci * 32 + lr) * 512];
        const ushort* krow1 = &Ks[(ci * 32 + 16 + lr) * 512];
#pragma unroll
        for (int ks = 0; ks < 16; ks += 2) {
            bf16x8 k0a = *(const bf16x8*)(krow0 + (((ks + 0) * 4 + lg) ^ zk) * 8);
            bf16x8 k0b = *(const bf16x8*)(krow0 + (((ks + 1) * 4 + lg) ^ zk) * 8);
            bf16x8 k1a = *(const bf16x8*)(krow1 + (((ks + 0) * 4 + lg) ^ zk) * 8);
            bf16x8 k1b = *(const bf16x8*)(krow1 + (((ks + 1) * 4 + lg) ^ zk) * 8);
            s0a = __builtin_amdgcn_mfma_f32_16x16x32_bf16(qf[ks + 0], k0a, s0a, 0, 0, 0);
            s0b = __builtin_amdgcn_mfma_f32_16x16x32_bf16(qf[ks + 1], k0b, s0b, 0, 0, 0);
            s1a = __builtin_amdgcn_mfma_f32_16x16x32_bf16(qf[ks + 0], k1a, s1a, 0, 0, 0);
            s1b = __builtin_amdgcn_mfma_f32_16x16x32_bf16(qf[ks + 1], k1b, s1b, 0, 0, 0);
        }
        f32x4 s0 = s0a + s0b;
        f32x4 s1 = s1a + s1b;
        float pm[4];
#pragma unroll
        for (int r = 0; r < 4; ++r) pm[r] = fmaxf(s0[r], s1[r]);
#pragma unroll
        for (int off = 1; off < 16; off <<= 1)
#pragma unroll
            for (int r = 0; r < 4; ++r) pm[r] = fmaxf(pm[r], __shfl_xor(pm[r], off));
        if (lr == 0) {
#pragma unroll
            for (int r = 0; r < 4; ++r) mpart[ci][mi][4 * lg + r] = pm[r];
        }
        asm volatile("s_waitcnt lgkmcnt(0)" ::: "memory");
        __builtin_amdgcn_s_barrier();
        __builtin_amdgcn_sched_barrier(0);
        if (nt + 1 < NT) stageK((nt + 1) * KVB);
        float mt2[4];
        float growth = -1e30f;
#pragma unroll
        for (int r = 0; r < 4; ++r) {
            int row = 4 * lg + r;
            mt2[r] = fmaxf(mpart[0][mi][row], mpart[1][mi][row]);
            growth = fmaxf(growth, mt2[r] - m_run[r]);
        }
        bool resc = !__all(growth <= 8.0f);
        if (resc) {
            float alpha[4];
#pragma unroll
            for (int r = 0; r < 4; ++r) {
                float mnew = fmaxf(m_run[r], mt2[r]);
                alpha[r] = __expf(m_run[r] - mnew);
                m_run[r] = mnew;
                lsum[r] *= alpha[r];
            }
#pragma unroll
            for (int cs = 0; cs < 16; ++cs) {
                acc[cs][0] *= alpha[0]; acc[cs][1] *= alpha[1];
                acc[cs][2] *= alpha[2]; acc[cs][3] *= alpha[3];
            }
        }
        float p0[4], p1[4];
#pragma unroll
        for (int r = 0; r < 4; ++r) {
            p0[r] = __expf(s0[r] - m_run[r]);
            p1[r] = __expf(s1[r] - m_run[r]);
            lsum[r] += p0[r] + p1[r];
        }
#pragma unroll
        for (int r = 0; r < 4; ++r) {
            int row = mi * 16 + 4 * lg + r;
            P_lds[row * 72 + ci * 32 + lr]      = f2b(p0[r]);
            P_lds[row * 72 + ci * 32 + 16 + lr] = f2b(p1[r]);
        }
        if (nt + 1 < NT) {
            asm volatile("s_waitcnt vmcnt(8)" ::: "memory");
        } else {
            asm volatile("s_waitcnt vmcnt(0)" ::: "memory");
        }
        asm volatile("s_waitcnt lgkmcnt(0)" ::: "memory");
        __builtin_amdgcn_s_barrier();
        __builtin_amdgcn_sched_barrier(0);
        bf16x8 pa0 = *(const bf16x8*)&P_lds[(mi * 16 + lr) * 72 + lg * 8];
        bf16x8 pa1 = *(const bf16x8*)&P_lds[(mi * 16 + lr) * 72 + 32 + lg * 8];
#pragma unroll
        for (int cs = 0; cs < 16; ++cs) {
            int c = ci * 256 + cs * 16 + lr;
            bf16x8 vf0 = *(const bf16x8*)&Vs[c * KVB + (((0 * 4 + lg) ^ (c & 7)) * 8)];
            bf16x8 vf1 = *(const bf16x8*)&Vs[c * KVB + (((1 * 4 + lg) ^ (c & 7)) * 8)];
            acc[cs] = __builtin_amdgcn_mfma_f32_16x16x32_bf16(pa0, vf0, acc[cs], 0, 0, 0);
            acc[cs] = __builtin_amdgcn_mfma_f32_16x16x32_bf16(pa1, vf1, acc[cs], 0, 0, 0);
        }
    }
    float ls[4];
#pragma unroll
    for (int r = 0; r < 4; ++r) ls[r] = lsum[r];
#pragma unroll
    for (int off = 1; off < 16; off <<= 1)
#pragma unroll
        for (int r = 0; r < 4; ++r) ls[r] += __shfl_xor(ls[r], off);
    if (lr == 0) {
#pragma unroll
        for (int r = 0; r < 4; ++r) mpart[ci][mi][4 * lg + r] = ls[r];
    }
    asm volatile("s_waitcnt lgkmcnt(0)" ::: "memory");
    __builtin_amdgcn_s_barrier();
    __builtin_amdgcn_sched_barrier(0);
    float inv[4];
#pragma unroll
    for (int r = 0; r < 4; ++r) {
        int row = 4 * lg + r;
        inv[r] = 1.0f / (mpart[0][mi][row] + mpart[1][mi][row]);
    }
#pragma unroll
    for (int cs = 0; cs < 16; ++cs)
#pragma unroll
        for (int r = 0; r < 4; ++r)
            aoT[((size_t)(b * NPOS + m0 + mi * 16 + 4 * lg + r)) * CH
                + ci * 256 + cs * 16 + lr] = f2b(acc[cs][r] * inv[r]);
}

// ---------------------------------------------------------------------------
// K5: proj on MFMA + bias + residual, depth-1 load pipeline.
// grid (64 mt, 8 ot, 4 b), 4 waves, wave tile 32o x 32m. No LDS.
// ---------------------------------------------------------------------------
__global__ __launch_bounds__(256) void proj_k(
    const ushort* __restrict__ aoT, const ushort* __restrict__ W4,
    const float* __restrict__ bp, const float* __restrict__ x,
    float* __restrict__ out) {
    int bm = blockIdx.x * 64, bo = blockIdx.y * 64, b = blockIdx.z;
    int t = threadIdx.x, l = t & 63, w = t >> 6;
    int orh = w & 1, mc = w >> 1;
    int lr = l & 15, lg = l >> 4;

    const ushort* wp = W4 + 3 * (size_t)WSZ + (size_t)(bo + orh * 32 + lr) * CH + lg * 8;
    const ushort* ab = aoT + ((size_t)(b * NPOS) + bm + mc * 32 + lr) * CH + lg * 8;

    f32x4 ac[2][2];
#pragma unroll
    for (int i = 0; i < 2; ++i)
#pragma unroll
        for (int j = 0; j < 2; ++j) ac[i][j] = (f32x4){0.f, 0.f, 0.f, 0.f};
    bf16x8 w0 = *(const bf16x8*)(wp);
    bf16x8 w1 = *(const bf16x8*)(wp + 16 * CH);
    bf16x8 b0 = *(const bf16x8*)(ab);
    bf16x8 b1 = *(const bf16x8*)(ab + 16 * CH);
#pragma unroll
    for (int s = 0; s < 16; ++s) {
        bf16x8 nw0, nw1, nb0, nb1;
        if (s < 15) {
            int c1 = (s + 1) * 32;
            nw0 = *(const bf16x8*)(wp + c1);
            nw1 = *(const bf16x8*)(wp + 16 * CH + c1);
            nb0 = *(const bf16x8*)(ab + c1);
            nb1 = *(const bf16x8*)(ab + 16 * CH + c1);
        }
        ac[0][0] = __builtin_amdgcn_mfma_f32_16x16x32_bf16(w0, b0, ac[0][0], 0, 0, 0);
        ac[0][1] = __builtin_amdgcn_mfma_f32_16x16x32_bf16(w0, b1, ac[0][1], 0, 0, 0);
        ac[1][0] = __builtin_amdgcn_mfma_f32_16x16x32_bf16(w1, b0, ac[1][0], 0, 0, 0);
        ac[1][1] = __builtin_amdgcn_mfma_f32_16x16x32_bf16(w1, b1, ac[1][1], 0, 0, 0);
        if (s < 15) { w0 = nw0; w1 = nw1; b0 = nb0; b1 = nb1; }
    }
#pragma unroll
    for (int i = 0; i < 2; ++i)
#pragma unroll
        for (int r = 0; r < 4; ++r) {
            int o = bo + orh * 32 + i * 16 + 4 * lg + r;
            float bpv = bp[o];
#pragma unroll
            for (int j = 0; j < 2; ++j) {
                int m = bm + mc * 32 + j * 16 + lr;
                size_t base = ((size_t)(b * CH) + o) * NPOS + m;
                out[base] = ac[i][j][r] + bpv + x[base];
            }
        }
}

// ---------------------------------------------------------------------------
extern "C" void kernel_launch(void* const* d_in, const int* in_sizes, int n_in,
                              void* d_out, int out_size, void* d_ws, size_t ws_size,
                              hipStream_t stream) {
    const float* x     = (const float*)d_in[0];
    const float* gamma = (const float*)d_in[1];
    const float* beta  = (const float*)d_in[2];
    const float* Wq    = (const float*)d_in[3];
    const float* bq    = (const float*)d_in[4];
    const float* Wk    = (const float*)d_in[5];
    const float* bk    = (const float*)d_in[6];
    const float* Wv    = (const float*)d_in[7];
    const float* bv    = (const float*)d_in[8];
    const float* Wp    = (const float*)d_in[9];
    const float* bp    = (const float*)d_in[10];
    float* out = (float*)d_out;

    const size_t SZ = (size_t)BATCH * CH * NPOS;               // 8,388,608
    const size_t need = (5 * SZ + 4 * WSZ) * 2 + 1024;         // ~86 MB
    if (ws_size < need) return;

    ushort* qT  = (ushort*)d_ws;          // [b][m][o] bf16 (pre-scaled)
    ushort* kT  = qT + SZ;                // [b][m][o] bf16
    ushort* vb  = kT + SZ;                // [b][o][m] bf16
    ushort* hnT = vb + SZ;                // [b][m][c] bf16
    ushort* aoT = hnT + SZ;               // [b][m][c] bf16
    ushort* W4  = aoT + SZ;               // [4][512][512] bf16
    float*  stats = (float*)(W4 + 4 * (size_t)WSZ);

    prep_k<<<640, 256, 0, stream>>>(x, stats, Wq, Wk, Wv, Wp, W4);
    hnT_k<<<dim3(64, 8, 4), 256, 0, stream>>>(x, gamma, beta, stats, hnT);
    qkv3_k<<<dim3(64, 8, 4), 256, 0, stream>>>(hnT, W4, bq, bk, bv, qT, kT, vb);
    attn_k<<<dim3(256), 512, 0, stream>>>(qT, kT, vb, aoT);
    proj_k<<<dim3(64, 8, 4), 256, 0, stream>>>(aoT, W4, bp, x, out);
}